// Round 7
// baseline (396.938 us; speedup 1.0000x reference)
//
#include <hip/hip_runtime.h>
#include <hip/hip_bf16.h>

// CrissCross attention, B=8 C=256 H=W=96 CQ=32. Flash-style split softmax, fp16
// operands everywhere (f16 MFMA = bf16 rate on gfx950, 8x less quant error):
//  pack_all : [wq|wk|wv] -> f16 Wall[320][256] + fp32 ball[320] per input
//  proj_all : one f16-MFMA pass, block (h,b): x row-tile staged once ->
//             q,k f16 Pt[b][n][64] (n-major) + v f16 vW[b][h][c][w]
//  vtrans   : vW* -> vH*[b][w][c][g], both pairs in one launch (z)
//  attn     : z=0 (b,h) e_w pass / z=1 (b,w) e_h pass (diag mask).
//             Fully direct-load/direct-store: QK^T MFMA from global Pt,
//             in-register wave softmax, probs via LDS (single sync),
//             PV MFMA with B-fragments straight from global V,
//             accumulator stored straight to tmp (ushort4) - no staging.
//  scl      : exact concat-softmax rescale sclH/sclW[b][h][w] (gamma folded)
//  tkomb    : out = x + tmpH^T*sclH + tmpW*sclW (transpose fused)

#define Bn 8
#define Cn 256
#define NHW 9216

typedef unsigned short u16;
typedef __attribute__((ext_vector_type(8))) _Float16 f16x8;
typedef __attribute__((ext_vector_type(4))) float f32x4;

__device__ __forceinline__ float h2f(u16 v) {
  _Float16 h;
  __builtin_memcpy(&h, &v, 2);
  return (float)h;
}
__device__ __forceinline__ u16 f2h(float f) {
  _Float16 h = (_Float16)f;
  u16 v;
  __builtin_memcpy(&v, &h, 2);
  return v;
}

__global__ __launch_bounds__(256) void pack_all(const float* __restrict__ wq, const float* __restrict__ bq,
                                                const float* __restrict__ wk, const float* __restrict__ bk,
                                                const float* __restrict__ wv, const float* __restrict__ bv,
                                                u16* __restrict__ Wall, float* __restrict__ ball) {
  int i = blockIdx.x * 256 + threadIdx.x;
  if (i < 320 * 256) {
    int o = i >> 8, c = i & 255;
    float v = (o < 32) ? wq[o * 256 + c] : (o < 64) ? wk[(o - 32) * 256 + c] : wv[(o - 64) * 256 + c];
    Wall[i] = f2h(v);
  }
  if (i < 320) ball[i] = (i < 32) ? bq[i] : (i < 64) ? bk[i - 32] : bv[i - 64];
}

// Fused projection: block (h, b). M=320 outputs, N=96 (one h-row), K=256, f16 MFMA.
// Wave w owns m-tiles {w, w+4, w+8, w+12, w+16}: first = qk, rest = v.
__global__ __launch_bounds__(256, 2) void proj_all(const float* __restrict__ X, const u16* __restrict__ Wall,
                                                   const float* __restrict__ ball, u16* __restrict__ Pt,
                                                   u16* __restrict__ vW) {
  __shared__ u16 xs[96][264];  // f16 x-tile [n][cin], 50688 B
  u16* sO = &xs[0][0];         // overlay [128][104] (26624 B) for v epilogue
  const int h = blockIdx.x, b = blockIdx.y;
  const int tid = threadIdx.x;
  const float* Xb = X + (size_t)b * Cn * NHW + h * 96;
  for (int idx = tid; idx < 6144; idx += 256) {
    int cin = idx / 24, n4 = idx % 24;
    float4 v = *(const float4*)(Xb + (size_t)cin * NHW + n4 * 4);
    xs[n4 * 4 + 0][cin] = f2h(v.x);
    xs[n4 * 4 + 1][cin] = f2h(v.y);
    xs[n4 * 4 + 2][cin] = f2h(v.z);
    xs[n4 * 4 + 3][cin] = f2h(v.w);
  }
  __syncthreads();
  const int lane = tid & 63, wv = tid >> 6;
  const int arow = lane & 15;
  const int g = lane >> 4;
  const int kc = g * 8;
  f32x4 acc[5][6] = {};
#pragma unroll
  for (int kk = 0; kk < 8; ++kk) {
    f16x8 a5[5], b6[6];
#pragma unroll
    for (int j = 0; j < 5; ++j)
      a5[j] = *(const f16x8*)(Wall + (size_t)((wv + 4 * j) * 16 + arow) * 256 + kk * 32 + kc);
#pragma unroll
    for (int nt = 0; nt < 6; ++nt)
      b6[nt] = *(const f16x8*)&xs[nt * 16 + arow][kk * 32 + kc];
#pragma unroll
    for (int j = 0; j < 5; ++j)
#pragma unroll
      for (int nt = 0; nt < 6; ++nt)
        acc[j][nt] = __builtin_amdgcn_mfma_f32_16x16x32_f16(a5[j], b6[nt], acc[j][nt], 0, 0, 0);
  }
  // qk epilogue: f16 Pt[b][n][o], o = wv*16 + 4g + rr
  {
    u16* Ptb = Pt + (size_t)b * ((size_t)NHW * 64);
    float4 bv = *(const float4*)(ball + wv * 16 + (g << 2));
#pragma unroll
    for (int nt = 0; nt < 6; ++nt) {
      int n = h * 96 + nt * 16 + arow;
      f32x4 a = acc[0][nt];
      ushort4 r;
      r.x = f2h(a[0] + bv.x); r.y = f2h(a[1] + bv.y);
      r.z = f2h(a[2] + bv.z); r.w = f2h(a[3] + bv.w);
      *(ushort4*)&Ptb[(size_t)n * 64 + wv * 16 + (g << 2)] = r;
    }
  }
  __syncthreads();
  // v epilogue: 2 rounds of 128 channels (j-tiles 2r+1, 2r+2)
  for (int r = 0; r < 2; ++r) {
#pragma unroll
    for (int jj = 0; jj < 2; ++jj) {
      int j = 2 * r + 1 + jj;
      float4 bv = *(const float4*)(ball + 64 + (j - 1) * 64 + wv * 16 + (g << 2));
      float ba[4] = {bv.x, bv.y, bv.z, bv.w};
#pragma unroll
      for (int nt = 0; nt < 6; ++nt) {
        int col = nt * 16 + arow;
#pragma unroll
        for (int rr = 0; rr < 4; ++rr) {
          int lrow = jj * 64 + wv * 16 + (g << 2) + rr;
          sO[lrow * 104 + col] = f2h(acc[j][nt][rr] + ba[rr]);
        }
      }
    }
    __syncthreads();
    for (int idx = tid; idx < 1536; idx += 256) {
      int cc = idx / 12, c4 = idx % 12;
      *(float4*)(vW + ((size_t)(b * 96 + h) * 256 + r * 128 + cc) * 96 + c4 * 8) =
          *(const float4*)&sO[cc * 104 + c4 * 8];
    }
    __syncthreads();
  }
}

// vH[b][w][c][g] = vW[b][g][c][w], both pairs (z selects)
__global__ __launch_bounds__(256) void vtrans(const u16* __restrict__ vW0, const u16* __restrict__ vW1,
                                              u16* __restrict__ vH0, u16* __restrict__ vH1) {
  __shared__ u16 t[96][98];
  const int c = blockIdx.x, b = blockIdx.y;
  const u16* vWp = blockIdx.z ? vW1 : vW0;
  u16* vHp = blockIdx.z ? vH1 : vH0;
  for (int idx = threadIdx.x; idx < 4608; idx += 256) {
    int hh = idx / 48, w2 = idx % 48;
    *(unsigned int*)&t[hh][w2 * 2] =
        *(const unsigned int*)(vWp + (size_t)(b * 96 + hh) * 24576 + c * 96 + w2 * 2);
  }
  __syncthreads();
  for (int idx = threadIdx.x; idx < 4608; idx += 256) {
    int ww = idx / 48, g2 = idx % 48;
    unsigned int lo = t[g2 * 2][ww];
    unsigned int hi = t[g2 * 2 + 1][ww];
    *(unsigned int*)(vHp + (size_t)(b * 96 + ww) * 24576 + c * 96 + g2 * 2) = lo | (hi << 16);
  }
}

// Merged attn: z=0 (b,h-row) e_w pass; z=1 (b,w-col) e_h pass (diag-masked).
// Direct-load QK^T (A,B 16B fragments from Pt), in-register softmax, probs->LDS,
// single sync, PV with B-fragments direct from V, accumulator stored direct.
__global__ __launch_bounds__(384) void attn_fused(const u16* __restrict__ Qpt, const u16* __restrict__ Kpt,
                                                  const u16* __restrict__ vWp, const u16* __restrict__ vHp,
                                                  float* __restrict__ mW, float* __restrict__ sW,
                                                  float* __restrict__ mH, float* __restrict__ sH,
                                                  u16* __restrict__ tmpW, u16* __restrict__ tmpH) {
  __shared__ u16 probs[96 * 104];  // 19968 B
  const int p = blockIdx.x, b = blockIdx.y, z = blockIdx.z;
  const int tid = threadIdx.x;
  const int lane = tid & 63, wv = tid >> 6;
  const int cl = lane & 15, g = lane >> 4;
  const int kc = g * 8;
  const int w0 = wv * 16;
  // row n of logit-index i: z=0 -> n = p*96+i ; z=1 -> n = i*96+p
  const size_t base = (size_t)b * ((size_t)NHW * 64) + (size_t)p * (z ? 64 : 6144);
  const size_t istride = z ? 6144 : 64;
  // QK^T: e[i = w0+4g+r][j = nt*16+cl]
  f32x4 eacc[6];
  {
    f16x8 aq = *(const f16x8*)(Qpt + base + (size_t)(w0 + cl) * istride + kc);
#pragma unroll
    for (int nt = 0; nt < 6; ++nt) {
      f16x8 bk = *(const f16x8*)(Kpt + base + (size_t)(nt * 16 + cl) * istride + 32 + kc);
      f32x4 zz = {0.f, 0.f, 0.f, 0.f};
      eacc[nt] = __builtin_amdgcn_mfma_f32_16x16x32_f16(aq, bk, zz, 0, 0, 0);
    }
  }
  // wave softmax per row r: max/sum across 6 nt + 16 col-lanes
#pragma unroll
  for (int r = 0; r < 4; ++r) {
    int i = w0 + 4 * g + r;
    float m = -1e30f;
#pragma unroll
    for (int nt = 0; nt < 6; ++nt) {
      float e = eacc[nt][r];
      if (z && (nt * 16 + cl) == i) { e = -1e30f; eacc[nt][r] = e; }
      m = fmaxf(m, e);
    }
    m = fmaxf(m, __shfl_xor(m, 1));
    m = fmaxf(m, __shfl_xor(m, 2));
    m = fmaxf(m, __shfl_xor(m, 4));
    m = fmaxf(m, __shfl_xor(m, 8));
    float s = 0.f;
#pragma unroll
    for (int nt = 0; nt < 6; ++nt) {
      float pv = __expf(eacc[nt][r] - m);
      eacc[nt][r] = pv;
      s += pv;
    }
    s += __shfl_xor(s, 1);
    s += __shfl_xor(s, 2);
    s += __shfl_xor(s, 4);
    s += __shfl_xor(s, 8);
#pragma unroll
    for (int nt = 0; nt < 6; ++nt)
      probs[i * 104 + nt * 16 + cl] = f2h(eacc[nt][r]);
    if (cl == 0) {
      size_t sidx = z ? ((size_t)(b * 96 + i) * 96 + p) : ((size_t)(b * 96 + p) * 96 + i);
      (z ? mH : mW)[sidx] = m;
      (z ? sH : sW)[sidx] = s;
    }
  }
  __syncthreads();
  // PV: out'[c][i] = sum_j probs[i][j] * V[c][j]; direct loads + direct stores.
  const u16* Vp = z ? vHp : vWp;
  u16* tOut = z ? tmpH : tmpW;
  const size_t vbase = (size_t)(b * 96 + p) * 24576;
  f16x8 af[3];
#pragma unroll
  for (int kt = 0; kt < 3; ++kt)
    af[kt] = *(const f16x8*)&probs[(w0 + cl) * 104 + kt * 32 + kc];
#pragma unroll
  for (int nt = 0; nt < 16; ++nt) {
    const int c = nt * 16 + cl;
    f32x4 a = {0.f, 0.f, 0.f, 0.f};
#pragma unroll
    for (int kt = 0; kt < 3; ++kt) {
      f16x8 bf = *(const f16x8*)(Vp + vbase + (size_t)c * 96 + kt * 32 + kc);
      a = __builtin_amdgcn_mfma_f32_16x16x32_f16(af[kt], bf, a, 0, 0, 0);
    }
    ushort4 r4;
    r4.x = f2h(a[0]); r4.y = f2h(a[1]); r4.z = f2h(a[2]); r4.w = f2h(a[3]);
    *(ushort4*)(tOut + vbase + (size_t)c * 96 + w0 + 4 * g) = r4;
  }
}

// Exact concat-softmax rescale: m=max(mh,mw), s=sh*e^(mh-m)+sw*e^(mw-m); scl*=gamma/s.
__global__ __launch_bounds__(256) void scl_k(const float* __restrict__ mH, const float* __restrict__ sH,
                                             const float* __restrict__ mW, const float* __restrict__ sW,
                                             const float* __restrict__ gammaP, float* __restrict__ sclH,
                                             float* __restrict__ sclW) {
  int i = blockIdx.x * 256 + threadIdx.x;
  if (i >= Bn * 9216) return;
  float mh = mH[i], mw = mW[i];
  float m = fmaxf(mh, mw);
  float eh = __expf(mh - m), ew = __expf(mw - m);
  float s = sH[i] * eh + sW[i] * ew;
  float g = gammaP[0] / s;
  sclH[i] = g * eh;
  sclW[i] = g * ew;
}

// out[b][c][h][w] = x + tmpH[b][w][c][h]*sclH[h][w] + tmpW[b][h][c][w]*sclW[h][w]
__global__ __launch_bounds__(256) void tkomb(const u16* __restrict__ tmpH, const u16* __restrict__ tmpW,
                                             const float* __restrict__ x, const float* __restrict__ sclH,
                                             const float* __restrict__ sclW, float* __restrict__ out) {
  __shared__ u16 t[96][108];
  const int c = blockIdx.x, b = blockIdx.y;
  const int tid = threadIdx.x;
  for (int idx = tid; idx < 2304; idx += 256) {
    int w_ = idx / 24, h4 = idx % 24;
    *(ushort4*)&t[w_][h4 * 4] =
        *(const ushort4*)(tmpH + ((size_t)(b * 96 + w_) * 256 + c) * 96 + h4 * 4);
  }
  __syncthreads();
  for (int idx = tid; idx < 2304; idx += 256) {
    int h_ = idx / 24, w4 = idx % 24;
    size_t go = ((size_t)(b * 256 + c) * 96 + h_) * 96 + w4 * 4;
    float4 xv = *(const float4*)(x + go);
    ushort4 wvv = *(const ushort4*)(tmpW + ((size_t)(b * 96 + h_) * 256 + c) * 96 + w4 * 4);
    float4 sh4 = *(const float4*)(sclH + (size_t)(b * 96 + h_) * 96 + w4 * 4);
    float4 sw4 = *(const float4*)(sclW + (size_t)(b * 96 + h_) * 96 + w4 * 4);
    float4 ov;
    ov.x = xv.x + h2f(t[w4 * 4 + 0][h_]) * sh4.x + h2f(wvv.x) * sw4.x;
    ov.y = xv.y + h2f(t[w4 * 4 + 1][h_]) * sh4.y + h2f(wvv.y) * sw4.y;
    ov.z = xv.z + h2f(t[w4 * 4 + 2][h_]) * sh4.z + h2f(wvv.z) * sw4.z;
    ov.w = xv.w + h2f(t[w4 * 4 + 3][h_]) * sh4.w + h2f(wvv.w) * sw4.w;
    *(float4*)(out + go) = ov;
  }
}

extern "C" void kernel_launch(void* const* d_in, const int* in_sizes, int n_in,
                              void* d_out, int out_size, void* d_ws, size_t ws_size,
                              hipStream_t stream) {
  const float* x0 = (const float*)d_in[0];
  const float* x1 = (const float*)d_in[1];
  const float* wq0 = (const float*)d_in[2];
  const float* bq0 = (const float*)d_in[3];
  const float* wk0 = (const float*)d_in[4];
  const float* bk0 = (const float*)d_in[5];
  const float* wv0 = (const float*)d_in[6];
  const float* bv0 = (const float*)d_in[7];
  const float* wq1 = (const float*)d_in[8];
  const float* bq1 = (const float*)d_in[9];
  const float* wk1 = (const float*)d_in[10];
  const float* bk1 = (const float*)d_in[11];
  const float* wv1 = (const float*)d_in[12];
  const float* bv1 = (const float*)d_in[13];
  const float* gamma = (const float*)d_in[14];
  float* out = (float*)d_out;

  char* ws = (char*)d_ws;
  size_t off = 0;
  auto alloc = [&](size_t bytes) -> void* {
    void* ptr = ws + off;
    off += (bytes + 255) & ~(size_t)255;
    return ptr;
  };
  const size_t SZ_P = (size_t)Bn * NHW * 64 * 2;   // 9.4 MB (f16)
  const size_t SZ_V = (size_t)Bn * NHW * Cn * 2;   // 37.7 MB
  const size_t SZ_S = (size_t)Bn * 9216 * 4;       // 294 KB
  u16* Pt0 = (u16*)alloc(SZ_P);
  u16* Pt1 = (u16*)alloc(SZ_P);
  u16* vW0 = (u16*)alloc(SZ_V);
  u16* vW1 = (u16*)alloc(SZ_V);
  u16* vH0 = (u16*)alloc(SZ_V);
  u16* vH1 = (u16*)alloc(SZ_V);
  u16* tmpW = (u16*)alloc(SZ_V);
  u16* tmpH = (u16*)alloc(SZ_V);
  u16* Wall0 = (u16*)alloc(320 * 256 * 2);
  u16* Wall1 = (u16*)alloc(320 * 256 * 2);
  float* ball0 = (float*)alloc(320 * 4);
  float* ball1 = (float*)alloc(320 * 4);
  float* mH = (float*)alloc(SZ_S);
  float* sH = (float*)alloc(SZ_S);
  float* mW = (float*)alloc(SZ_S);
  float* sW = (float*)alloc(SZ_S);
  float* sclH = (float*)alloc(SZ_S);
  float* sclW = (float*)alloc(SZ_S);
  (void)ws_size; (void)in_sizes; (void)n_in; (void)out_size;

  pack_all<<<320, 256, 0, stream>>>(wq0, bq0, wk0, bk0, wv0, bv0, Wall0, ball0);
  pack_all<<<320, 256, 0, stream>>>(wq1, bq1, wk1, bk1, wv1, bv1, Wall1, ball1);

  dim3 gp(96, Bn), gc(256, Bn), gt(256, Bn, 2), ga(96, Bn, 2);
  proj_all<<<gp, 256, 0, stream>>>(x0, Wall0, ball0, Pt0, vW0);
  proj_all<<<gp, 256, 0, stream>>>(x1, Wall1, ball1, Pt1, vW1);
  vtrans<<<gt, 256, 0, stream>>>(vW0, vW1, vH0, vH1);

  // pair 0: cat0 = gamma * attend(q1, k0, v0) + x0
  attn_fused<<<ga, 384, 0, stream>>>(Pt1, Pt0, vW0, vH0, mW, sW, mH, sH, tmpW, tmpH);
  scl_k<<<288, 256, 0, stream>>>(mH, sH, mW, sW, gamma, sclH, sclW);
  tkomb<<<gc, 256, 0, stream>>>(tmpH, tmpW, x0, sclH, sclW, out);

  // pair 1: cat1 = gamma * attend(q0, k1, v1) + x1
  attn_fused<<<ga, 384, 0, stream>>>(Pt0, Pt1, vW1, vH1, mW, sW, mH, sH, tmpW, tmpH);
  scl_k<<<288, 256, 0, stream>>>(mH, sH, mW, sW, gamma, sclH, sclW);
  tkomb<<<gc, 256, 0, stream>>>(tmpH, tmpW, x1, sclH, sclW, out + (size_t)Bn * Cn * NHW);
}

// Round 8
// 391.618 us; speedup vs baseline: 1.0136x; 1.0136x over previous
//
#include <hip/hip_runtime.h>
#include <hip/hip_bf16.h>

// CrissCross attention, B=8 C=256 H=W=96 CQ=32. Flash-style split softmax, fp16
// operands everywhere (f16 MFMA = bf16 rate on gfx950, 8x less quant error):
//  pack_all : [wq|wk|wv] -> f16 Wall[320][256] + fp32 ball[320] per input
//  proj_all : one f16-MFMA pass, block (h,b): x row-tile staged once ->
//             q,k f16 Pt[b][n][64] (n-major) + v f16 vW[b][h][c][w]
//  vtrans   : vW* -> vH*[b][w][c][g], both pairs in one launch (z)
//  attn     : z=0 (b,h) e_w pass / z=1 (b,w) e_h pass (diag mask).
//             Direct QK^T loads from Pt, in-register wave softmax, probs->LDS;
//             V staged in LDS via register-prefetched bulk loads (issued under
//             QK^T/softmax and under the previous half's MFMAs; 3 barriers),
//             PV MFMA from LDS, accumulator stored direct (ushort4).
//  scl      : exact concat-softmax rescale sclH/sclW[b][h][w] (gamma folded)
//  tkomb    : out = x + tmpH^T*sclH + tmpW*sclW (transpose fused)

#define Bn 8
#define Cn 256
#define NHW 9216

typedef unsigned short u16;
typedef __attribute__((ext_vector_type(8))) _Float16 f16x8;
typedef __attribute__((ext_vector_type(4))) float f32x4;

__device__ __forceinline__ float h2f(u16 v) {
  _Float16 h;
  __builtin_memcpy(&h, &v, 2);
  return (float)h;
}
__device__ __forceinline__ u16 f2h(float f) {
  _Float16 h = (_Float16)f;
  u16 v;
  __builtin_memcpy(&v, &h, 2);
  return v;
}

__global__ __launch_bounds__(256) void pack_all(const float* __restrict__ wq, const float* __restrict__ bq,
                                                const float* __restrict__ wk, const float* __restrict__ bk,
                                                const float* __restrict__ wv, const float* __restrict__ bv,
                                                u16* __restrict__ Wall, float* __restrict__ ball) {
  int i = blockIdx.x * 256 + threadIdx.x;
  if (i < 320 * 256) {
    int o = i >> 8, c = i & 255;
    float v = (o < 32) ? wq[o * 256 + c] : (o < 64) ? wk[(o - 32) * 256 + c] : wv[(o - 64) * 256 + c];
    Wall[i] = f2h(v);
  }
  if (i < 320) ball[i] = (i < 32) ? bq[i] : (i < 64) ? bk[i - 32] : bv[i - 64];
}

// Fused projection: block (h, b). M=320 outputs, N=96 (one h-row), K=256, f16 MFMA.
// Wave w owns m-tiles {w, w+4, w+8, w+12, w+16}: first = qk, rest = v.
__global__ __launch_bounds__(256, 2) void proj_all(const float* __restrict__ X, const u16* __restrict__ Wall,
                                                   const float* __restrict__ ball, u16* __restrict__ Pt,
                                                   u16* __restrict__ vW) {
  __shared__ u16 xs[96][264];  // f16 x-tile [n][cin], 50688 B
  u16* sO = &xs[0][0];         // overlay [128][104] (26624 B) for v epilogue
  const int h = blockIdx.x, b = blockIdx.y;
  const int tid = threadIdx.x;
  const float* Xb = X + (size_t)b * Cn * NHW + h * 96;
  for (int idx = tid; idx < 6144; idx += 256) {
    int cin = idx / 24, n4 = idx % 24;
    float4 v = *(const float4*)(Xb + (size_t)cin * NHW + n4 * 4);
    xs[n4 * 4 + 0][cin] = f2h(v.x);
    xs[n4 * 4 + 1][cin] = f2h(v.y);
    xs[n4 * 4 + 2][cin] = f2h(v.z);
    xs[n4 * 4 + 3][cin] = f2h(v.w);
  }
  __syncthreads();
  const int lane = tid & 63, wv = tid >> 6;
  const int arow = lane & 15;
  const int g = lane >> 4;
  const int kc = g * 8;
  f32x4 acc[5][6] = {};
#pragma unroll
  for (int kk = 0; kk < 8; ++kk) {
    f16x8 a5[5], b6[6];
#pragma unroll
    for (int j = 0; j < 5; ++j)
      a5[j] = *(const f16x8*)(Wall + (size_t)((wv + 4 * j) * 16 + arow) * 256 + kk * 32 + kc);
#pragma unroll
    for (int nt = 0; nt < 6; ++nt)
      b6[nt] = *(const f16x8*)&xs[nt * 16 + arow][kk * 32 + kc];
#pragma unroll
    for (int j = 0; j < 5; ++j)
#pragma unroll
      for (int nt = 0; nt < 6; ++nt)
        acc[j][nt] = __builtin_amdgcn_mfma_f32_16x16x32_f16(a5[j], b6[nt], acc[j][nt], 0, 0, 0);
  }
  // qk epilogue: f16 Pt[b][n][o], o = wv*16 + 4g + rr
  {
    u16* Ptb = Pt + (size_t)b * ((size_t)NHW * 64);
    float4 bv = *(const float4*)(ball + wv * 16 + (g << 2));
#pragma unroll
    for (int nt = 0; nt < 6; ++nt) {
      int n = h * 96 + nt * 16 + arow;
      f32x4 a = acc[0][nt];
      ushort4 r;
      r.x = f2h(a[0] + bv.x); r.y = f2h(a[1] + bv.y);
      r.z = f2h(a[2] + bv.z); r.w = f2h(a[3] + bv.w);
      *(ushort4*)&Ptb[(size_t)n * 64 + wv * 16 + (g << 2)] = r;
    }
  }
  __syncthreads();
  // v epilogue: 2 rounds of 128 channels (j-tiles 2r+1, 2r+2)
  for (int r = 0; r < 2; ++r) {
#pragma unroll
    for (int jj = 0; jj < 2; ++jj) {
      int j = 2 * r + 1 + jj;
      float4 bv = *(const float4*)(ball + 64 + (j - 1) * 64 + wv * 16 + (g << 2));
      float ba[4] = {bv.x, bv.y, bv.z, bv.w};
#pragma unroll
      for (int nt = 0; nt < 6; ++nt) {
        int col = nt * 16 + arow;
#pragma unroll
        for (int rr = 0; rr < 4; ++rr) {
          int lrow = jj * 64 + wv * 16 + (g << 2) + rr;
          sO[lrow * 104 + col] = f2h(acc[j][nt][rr] + ba[rr]);
        }
      }
    }
    __syncthreads();
    for (int idx = tid; idx < 1536; idx += 256) {
      int cc = idx / 12, c4 = idx % 12;
      *(float4*)(vW + ((size_t)(b * 96 + h) * 256 + r * 128 + cc) * 96 + c4 * 8) =
          *(const float4*)&sO[cc * 104 + c4 * 8];
    }
    __syncthreads();
  }
}

// vH[b][w][c][g] = vW[b][g][c][w], both pairs (z selects)
__global__ __launch_bounds__(256) void vtrans(const u16* __restrict__ vW0, const u16* __restrict__ vW1,
                                              u16* __restrict__ vH0, u16* __restrict__ vH1) {
  __shared__ u16 t[96][98];
  const int c = blockIdx.x, b = blockIdx.y;
  const u16* vWp = blockIdx.z ? vW1 : vW0;
  u16* vHp = blockIdx.z ? vH1 : vH0;
  for (int idx = threadIdx.x; idx < 4608; idx += 256) {
    int hh = idx / 48, w2 = idx % 48;
    *(unsigned int*)&t[hh][w2 * 2] =
        *(const unsigned int*)(vWp + (size_t)(b * 96 + hh) * 24576 + c * 96 + w2 * 2);
  }
  __syncthreads();
  for (int idx = threadIdx.x; idx < 4608; idx += 256) {
    int ww = idx / 48, g2 = idx % 48;
    unsigned int lo = t[g2 * 2][ww];
    unsigned int hi = t[g2 * 2 + 1][ww];
    *(unsigned int*)(vHp + (size_t)(b * 96 + ww) * 24576 + c * 96 + g2 * 2) = lo | (hi << 16);
  }
}

// Merged attn: z=0 (b,h-row) e_w pass; z=1 (b,w-col) e_h pass (diag-masked).
// QK^T direct from Pt; V half-tiles register-prefetched into LDS; 3 barriers.
__global__ __launch_bounds__(384, 3) void attn_fused(const u16* __restrict__ Qpt, const u16* __restrict__ Kpt,
                                                     const u16* __restrict__ vWp, const u16* __restrict__ vHp,
                                                     float* __restrict__ mW, float* __restrict__ sW,
                                                     float* __restrict__ mH, float* __restrict__ sH,
                                                     u16* __restrict__ tmpW, u16* __restrict__ tmpH) {
  __shared__ u16 probs[96 * 104];  // 19968 B
  __shared__ u16 vbuf[128 * 104];  // 26624 B
  const int p = blockIdx.x, b = blockIdx.y, z = blockIdx.z;
  const int tid = threadIdx.x;
  const int lane = tid & 63, wv = tid >> 6;
  const int cl = lane & 15, g = lane >> 4;
  const int kc = g * 8;
  const int w0 = wv * 16;
  const u16* Vp = z ? vHp : vWp;
  u16* tOut = z ? tmpH : tmpW;
  const size_t vbase = (size_t)(b * 96 + p) * 24576;
  // prefetch half-0 V tile into regs (hides under QK^T + softmax)
  const int ldr = tid / 12, ldc = (tid % 12) * 8;  // row 0..127(+256), col-8-group
  float4 vpre[4];
#pragma unroll
  for (int i = 0; i < 4; ++i) {
    int r = ldr + (i & 1) * 256;  // rows: tid/12 in [0,32), +32*i pattern below
    (void)r;
  }
  // 1536 float4 per half, 384 threads -> 4 each: rows tid/12 + 32*i
#pragma unroll
  for (int i = 0; i < 4; ++i)
    vpre[i] = *(const float4*)(Vp + vbase + (size_t)(ldr + 32 * i) * 96 + ldc);
  // row n of logit-index i: z=0 -> n = p*96+i ; z=1 -> n = i*96+p
  const size_t base = (size_t)b * ((size_t)NHW * 64) + (size_t)p * (z ? 64 : 6144);
  const size_t istride = z ? 6144 : 64;
  // QK^T: e[i = w0+4g+r][j = nt*16+cl]
  f32x4 eacc[6];
  {
    f16x8 aq = *(const f16x8*)(Qpt + base + (size_t)(w0 + cl) * istride + kc);
#pragma unroll
    for (int nt = 0; nt < 6; ++nt) {
      f16x8 bk = *(const f16x8*)(Kpt + base + (size_t)(nt * 16 + cl) * istride + 32 + kc);
      f32x4 zz = {0.f, 0.f, 0.f, 0.f};
      eacc[nt] = __builtin_amdgcn_mfma_f32_16x16x32_f16(aq, bk, zz, 0, 0, 0);
    }
  }
  // wave softmax per row r: max/sum across 6 nt + 16 col-lanes
#pragma unroll
  for (int r = 0; r < 4; ++r) {
    int i = w0 + 4 * g + r;
    float m = -1e30f;
#pragma unroll
    for (int nt = 0; nt < 6; ++nt) {
      float e = eacc[nt][r];
      if (z && (nt * 16 + cl) == i) { e = -1e30f; eacc[nt][r] = e; }
      m = fmaxf(m, e);
    }
    m = fmaxf(m, __shfl_xor(m, 1));
    m = fmaxf(m, __shfl_xor(m, 2));
    m = fmaxf(m, __shfl_xor(m, 4));
    m = fmaxf(m, __shfl_xor(m, 8));
    float s = 0.f;
#pragma unroll
    for (int nt = 0; nt < 6; ++nt) {
      float pv = __expf(eacc[nt][r] - m);
      eacc[nt][r] = pv;
      s += pv;
    }
    s += __shfl_xor(s, 1);
    s += __shfl_xor(s, 2);
    s += __shfl_xor(s, 4);
    s += __shfl_xor(s, 8);
#pragma unroll
    for (int nt = 0; nt < 6; ++nt)
      probs[i * 104 + nt * 16 + cl] = f2h(eacc[nt][r]);
    if (cl == 0) {
      size_t sidx = z ? ((size_t)(b * 96 + i) * 96 + p) : ((size_t)(b * 96 + p) * 96 + i);
      (z ? mH : mW)[sidx] = m;
      (z ? sH : sW)[sidx] = s;
    }
  }
  // write prefetched half-0 into LDS; one barrier covers probs + vbuf
#pragma unroll
  for (int i = 0; i < 4; ++i)
    *(float4*)&vbuf[(ldr + 32 * i) * 104 + ldc] = vpre[i];
  __syncthreads();
  f16x8 af[3];
#pragma unroll
  for (int kt = 0; kt < 3; ++kt)
    af[kt] = *(const f16x8*)&probs[(w0 + cl) * 104 + kt * 32 + kc];
  // issue half-1 prefetch before half-0 MFMAs
#pragma unroll
  for (int i = 0; i < 4; ++i)
    vpre[i] = *(const float4*)(Vp + vbase + (size_t)(128 + ldr + 32 * i) * 96 + ldc);
  // half-0 PV: out'[c][i], c in [0,128)
#pragma unroll
  for (int nt = 0; nt < 8; ++nt) {
    const int c = nt * 16 + cl;
    f32x4 a = {0.f, 0.f, 0.f, 0.f};
#pragma unroll
    for (int kt = 0; kt < 3; ++kt) {
      f16x8 bf = *(const f16x8*)&vbuf[c * 104 + kt * 32 + kc];
      a = __builtin_amdgcn_mfma_f32_16x16x32_f16(af[kt], bf, a, 0, 0, 0);
    }
    ushort4 r4;
    r4.x = f2h(a[0]); r4.y = f2h(a[1]); r4.z = f2h(a[2]); r4.w = f2h(a[3]);
    *(ushort4*)(tOut + vbase + (size_t)c * 96 + w0 + 4 * g) = r4;
  }
  __syncthreads();
#pragma unroll
  for (int i = 0; i < 4; ++i)
    *(float4*)&vbuf[(ldr + 32 * i) * 104 + ldc] = vpre[i];
  __syncthreads();
  // half-1 PV: c in [128,256)
#pragma unroll
  for (int nt = 0; nt < 8; ++nt) {
    const int c = nt * 16 + cl;
    f32x4 a = {0.f, 0.f, 0.f, 0.f};
#pragma unroll
    for (int kt = 0; kt < 3; ++kt) {
      f16x8 bf = *(const f16x8*)&vbuf[c * 104 + kt * 32 + kc];
      a = __builtin_amdgcn_mfma_f32_16x16x32_f16(af[kt], bf, a, 0, 0, 0);
    }
    ushort4 r4;
    r4.x = f2h(a[0]); r4.y = f2h(a[1]); r4.z = f2h(a[2]); r4.w = f2h(a[3]);
    *(ushort4*)(tOut + vbase + (size_t)(128 + c) * 96 + w0 + 4 * g) = r4;
  }
}

// Exact concat-softmax rescale: m=max(mh,mw), s=sh*e^(mh-m)+sw*e^(mw-m); scl*=gamma/s.
__global__ __launch_bounds__(256) void scl_k(const float* __restrict__ mH, const float* __restrict__ sH,
                                             const float* __restrict__ mW, const float* __restrict__ sW,
                                             const float* __restrict__ gammaP, float* __restrict__ sclH,
                                             float* __restrict__ sclW) {
  int i = blockIdx.x * 256 + threadIdx.x;
  if (i >= Bn * 9216) return;
  float mh = mH[i], mw = mW[i];
  float m = fmaxf(mh, mw);
  float eh = __expf(mh - m), ew = __expf(mw - m);
  float s = sH[i] * eh + sW[i] * ew;
  float g = gammaP[0] / s;
  sclH[i] = g * eh;
  sclW[i] = g * ew;
}

// out[b][c][h][w] = x + tmpH[b][w][c][h]*sclH[h][w] + tmpW[b][h][c][w]*sclW[h][w]
__global__ __launch_bounds__(256) void tkomb(const u16* __restrict__ tmpH, const u16* __restrict__ tmpW,
                                             const float* __restrict__ x, const float* __restrict__ sclH,
                                             const float* __restrict__ sclW, float* __restrict__ out) {
  __shared__ u16 t[96][108];
  const int c = blockIdx.x, b = blockIdx.y;
  const int tid = threadIdx.x;
  for (int idx = tid; idx < 2304; idx += 256) {
    int w_ = idx / 24, h4 = idx % 24;
    *(ushort4*)&t[w_][h4 * 4] =
        *(const ushort4*)(tmpH + ((size_t)(b * 96 + w_) * 256 + c) * 96 + h4 * 4);
  }
  __syncthreads();
  for (int idx = tid; idx < 2304; idx += 256) {
    int h_ = idx / 24, w4 = idx % 24;
    size_t go = ((size_t)(b * 256 + c) * 96 + h_) * 96 + w4 * 4;
    float4 xv = *(const float4*)(x + go);
    ushort4 wvv = *(const ushort4*)(tmpW + ((size_t)(b * 96 + h_) * 256 + c) * 96 + w4 * 4);
    float4 sh4 = *(const float4*)(sclH + (size_t)(b * 96 + h_) * 96 + w4 * 4);
    float4 sw4 = *(const float4*)(sclW + (size_t)(b * 96 + h_) * 96 + w4 * 4);
    float4 ov;
    ov.x = xv.x + h2f(t[w4 * 4 + 0][h_]) * sh4.x + h2f(wvv.x) * sw4.x;
    ov.y = xv.y + h2f(t[w4 * 4 + 1][h_]) * sh4.y + h2f(wvv.y) * sw4.y;
    ov.z = xv.z + h2f(t[w4 * 4 + 2][h_]) * sh4.z + h2f(wvv.z) * sw4.z;
    ov.w = xv.w + h2f(t[w4 * 4 + 3][h_]) * sh4.w + h2f(wvv.w) * sw4.w;
    *(float4*)(out + go) = ov;
  }
}

extern "C" void kernel_launch(void* const* d_in, const int* in_sizes, int n_in,
                              void* d_out, int out_size, void* d_ws, size_t ws_size,
                              hipStream_t stream) {
  const float* x0 = (const float*)d_in[0];
  const float* x1 = (const float*)d_in[1];
  const float* wq0 = (const float*)d_in[2];
  const float* bq0 = (const float*)d_in[3];
  const float* wk0 = (const float*)d_in[4];
  const float* bk0 = (const float*)d_in[5];
  const float* wv0 = (const float*)d_in[6];
  const float* bv0 = (const float*)d_in[7];
  const float* wq1 = (const float*)d_in[8];
  const float* bq1 = (const float*)d_in[9];
  const float* wk1 = (const float*)d_in[10];
  const float* bk1 = (const float*)d_in[11];
  const float* wv1 = (const float*)d_in[12];
  const float* bv1 = (const float*)d_in[13];
  const float* gamma = (const float*)d_in[14];
  float* out = (float*)d_out;

  char* ws = (char*)d_ws;
  size_t off = 0;
  auto alloc = [&](size_t bytes) -> void* {
    void* ptr = ws + off;
    off += (bytes + 255) & ~(size_t)255;
    return ptr;
  };
  const size_t SZ_P = (size_t)Bn * NHW * 64 * 2;   // 9.4 MB (f16)
  const size_t SZ_V = (size_t)Bn * NHW * Cn * 2;   // 37.7 MB
  const size_t SZ_S = (size_t)Bn * 9216 * 4;       // 294 KB
  u16* Pt0 = (u16*)alloc(SZ_P);
  u16* Pt1 = (u16*)alloc(SZ_P);
  u16* vW0 = (u16*)alloc(SZ_V);
  u16* vW1 = (u16*)alloc(SZ_V);
  u16* vH0 = (u16*)alloc(SZ_V);
  u16* vH1 = (u16*)alloc(SZ_V);
  u16* tmpW = (u16*)alloc(SZ_V);
  u16* tmpH = (u16*)alloc(SZ_V);
  u16* Wall0 = (u16*)alloc(320 * 256 * 2);
  u16* Wall1 = (u16*)alloc(320 * 256 * 2);
  float* ball0 = (float*)alloc(320 * 4);
  float* ball1 = (float*)alloc(320 * 4);
  float* mH = (float*)alloc(SZ_S);
  float* sH = (float*)alloc(SZ_S);
  float* mW = (float*)alloc(SZ_S);
  float* sW = (float*)alloc(SZ_S);
  float* sclH = (float*)alloc(SZ_S);
  float* sclW = (float*)alloc(SZ_S);
  (void)ws_size; (void)in_sizes; (void)n_in; (void)out_size;

  pack_all<<<320, 256, 0, stream>>>(wq0, bq0, wk0, bk0, wv0, bv0, Wall0, ball0);
  pack_all<<<320, 256, 0, stream>>>(wq1, bq1, wk1, bk1, wv1, bv1, Wall1, ball1);

  dim3 gp(96, Bn), gc(256, Bn), gt(256, Bn, 2), ga(96, Bn, 2);
  proj_all<<<gp, 256, 0, stream>>>(x0, Wall0, ball0, Pt0, vW0);
  proj_all<<<gp, 256, 0, stream>>>(x1, Wall1, ball1, Pt1, vW1);
  vtrans<<<gt, 256, 0, stream>>>(vW0, vW1, vH0, vH1);

  // pair 0: cat0 = gamma * attend(q1, k0, v0) + x0
  attn_fused<<<ga, 384, 0, stream>>>(Pt1, Pt0, vW0, vH0, mW, sW, mH, sH, tmpW, tmpH);
  scl_k<<<288, 256, 0, stream>>>(mH, sH, mW, sW, gamma, sclH, sclW);
  tkomb<<<gc, 256, 0, stream>>>(tmpH, tmpW, x0, sclH, sclW, out);

  // pair 1: cat1 = gamma * attend(q0, k1, v1) + x1
  attn_fused<<<ga, 384, 0, stream>>>(Pt0, Pt1, vW1, vH1, mW, sW, mH, sH, tmpW, tmpH);
  scl_k<<<288, 256, 0, stream>>>(mH, sH, mW, sW, gamma, sclH, sclW);
  tkomb<<<gc, 256, 0, stream>>>(tmpH, tmpW, x1, sclH, sclW, out + (size_t)Bn * Cn * NHW);
}

// Round 9
// 373.970 us; speedup vs baseline: 1.0614x; 1.0472x over previous
//
#include <hip/hip_runtime.h>
#include <hip/hip_bf16.h>

// CrissCross attention, B=8 C=256 H=W=96 CQ=32. Flash-style split softmax, fp16
// operands everywhere (f16 MFMA = bf16 rate on gfx950, 8x less quant error):
//  pack_all : [wq|wk|wv] -> f16 Wall[320][256] + fp32 ball[320] per input
//  proj_all : one f16-MFMA pass, block (h,b): x row-tile staged once ->
//             q,k f16 Pt[b][n][64] (n-major) + v f16 vW[b][h][c][w]
//  vtrans   : vW* -> vH*[b][w][c][g], both pairs in one launch (z)
//  attn     : z=0 (b,h) e_w pass / z=1 (b,w) e_h pass (diag mask).
//             Direct QK^T loads from Pt, in-register wave softmax, probs->LDS;
//             V half-tiles register-prefetched into LDS (loads issued a full
//             phase ahead); PV MFMA from LDS; accumulator goes through an LDS
//             transpose so stores are coalesced 192B float4 row runs
//             (round-7/8 lesson: direct 8B stores = 2x write amplification).
//  scl      : exact concat-softmax rescale sclH/sclW[b][h][w] (gamma folded)
//  tkomb    : out = x + tmpH^T*sclH + tmpW*sclW (transpose fused)

#define Bn 8
#define Cn 256
#define NHW 9216

typedef unsigned short u16;
typedef __attribute__((ext_vector_type(8))) _Float16 f16x8;
typedef __attribute__((ext_vector_type(4))) float f32x4;

__device__ __forceinline__ float h2f(u16 v) {
  _Float16 h;
  __builtin_memcpy(&h, &v, 2);
  return (float)h;
}
__device__ __forceinline__ u16 f2h(float f) {
  _Float16 h = (_Float16)f;
  u16 v;
  __builtin_memcpy(&v, &h, 2);
  return v;
}

__global__ __launch_bounds__(256) void pack_all(const float* __restrict__ wq, const float* __restrict__ bq,
                                                const float* __restrict__ wk, const float* __restrict__ bk,
                                                const float* __restrict__ wv, const float* __restrict__ bv,
                                                u16* __restrict__ Wall, float* __restrict__ ball) {
  int i = blockIdx.x * 256 + threadIdx.x;
  if (i < 320 * 256) {
    int o = i >> 8, c = i & 255;
    float v = (o < 32) ? wq[o * 256 + c] : (o < 64) ? wk[(o - 32) * 256 + c] : wv[(o - 64) * 256 + c];
    Wall[i] = f2h(v);
  }
  if (i < 320) ball[i] = (i < 32) ? bq[i] : (i < 64) ? bk[i - 32] : bv[i - 64];
}

// Fused projection: block (h, b). M=320 outputs, N=96 (one h-row), K=256, f16 MFMA.
// Wave w owns m-tiles {w, w+4, w+8, w+12, w+16}: first = qk, rest = v.
__global__ __launch_bounds__(256, 2) void proj_all(const float* __restrict__ X, const u16* __restrict__ Wall,
                                                   const float* __restrict__ ball, u16* __restrict__ Pt,
                                                   u16* __restrict__ vW) {
  __shared__ u16 xs[96][264];  // f16 x-tile [n][cin], 50688 B
  u16* sO = &xs[0][0];         // overlay [128][104] (26624 B) for v epilogue
  const int h = blockIdx.x, b = blockIdx.y;
  const int tid = threadIdx.x;
  const float* Xb = X + (size_t)b * Cn * NHW + h * 96;
  for (int idx = tid; idx < 6144; idx += 256) {
    int cin = idx / 24, n4 = idx % 24;
    float4 v = *(const float4*)(Xb + (size_t)cin * NHW + n4 * 4);
    xs[n4 * 4 + 0][cin] = f2h(v.x);
    xs[n4 * 4 + 1][cin] = f2h(v.y);
    xs[n4 * 4 + 2][cin] = f2h(v.z);
    xs[n4 * 4 + 3][cin] = f2h(v.w);
  }
  __syncthreads();
  const int lane = tid & 63, wv = tid >> 6;
  const int arow = lane & 15;
  const int g = lane >> 4;
  const int kc = g * 8;
  f32x4 acc[5][6] = {};
#pragma unroll
  for (int kk = 0; kk < 8; ++kk) {
    f16x8 a5[5], b6[6];
#pragma unroll
    for (int j = 0; j < 5; ++j)
      a5[j] = *(const f16x8*)(Wall + (size_t)((wv + 4 * j) * 16 + arow) * 256 + kk * 32 + kc);
#pragma unroll
    for (int nt = 0; nt < 6; ++nt)
      b6[nt] = *(const f16x8*)&xs[nt * 16 + arow][kk * 32 + kc];
#pragma unroll
    for (int j = 0; j < 5; ++j)
#pragma unroll
      for (int nt = 0; nt < 6; ++nt)
        acc[j][nt] = __builtin_amdgcn_mfma_f32_16x16x32_f16(a5[j], b6[nt], acc[j][nt], 0, 0, 0);
  }
  // qk epilogue: f16 Pt[b][n][o], o = wv*16 + 4g + rr
  {
    u16* Ptb = Pt + (size_t)b * ((size_t)NHW * 64);
    float4 bv = *(const float4*)(ball + wv * 16 + (g << 2));
#pragma unroll
    for (int nt = 0; nt < 6; ++nt) {
      int n = h * 96 + nt * 16 + arow;
      f32x4 a = acc[0][nt];
      ushort4 r;
      r.x = f2h(a[0] + bv.x); r.y = f2h(a[1] + bv.y);
      r.z = f2h(a[2] + bv.z); r.w = f2h(a[3] + bv.w);
      *(ushort4*)&Ptb[(size_t)n * 64 + wv * 16 + (g << 2)] = r;
    }
  }
  __syncthreads();
  // v epilogue: 2 rounds of 128 channels (j-tiles 2r+1, 2r+2)
  for (int r = 0; r < 2; ++r) {
#pragma unroll
    for (int jj = 0; jj < 2; ++jj) {
      int j = 2 * r + 1 + jj;
      float4 bv = *(const float4*)(ball + 64 + (j - 1) * 64 + wv * 16 + (g << 2));
      float ba[4] = {bv.x, bv.y, bv.z, bv.w};
#pragma unroll
      for (int nt = 0; nt < 6; ++nt) {
        int col = nt * 16 + arow;
#pragma unroll
        for (int rr = 0; rr < 4; ++rr) {
          int lrow = jj * 64 + wv * 16 + (g << 2) + rr;
          sO[lrow * 104 + col] = f2h(acc[j][nt][rr] + ba[rr]);
        }
      }
    }
    __syncthreads();
    for (int idx = tid; idx < 1536; idx += 256) {
      int cc = idx / 12, c4 = idx % 12;
      *(float4*)(vW + ((size_t)(b * 96 + h) * 256 + r * 128 + cc) * 96 + c4 * 8) =
          *(const float4*)&sO[cc * 104 + c4 * 8];
    }
    __syncthreads();
  }
}

// vH[b][w][c][g] = vW[b][g][c][w], both pairs (z selects)
__global__ __launch_bounds__(256) void vtrans(const u16* __restrict__ vW0, const u16* __restrict__ vW1,
                                              u16* __restrict__ vH0, u16* __restrict__ vH1) {
  __shared__ u16 t[96][98];
  const int c = blockIdx.x, b = blockIdx.y;
  const u16* vWp = blockIdx.z ? vW1 : vW0;
  u16* vHp = blockIdx.z ? vH1 : vH0;
  for (int idx = threadIdx.x; idx < 4608; idx += 256) {
    int hh = idx / 48, w2 = idx % 48;
    *(unsigned int*)&t[hh][w2 * 2] =
        *(const unsigned int*)(vWp + (size_t)(b * 96 + hh) * 24576 + c * 96 + w2 * 2);
  }
  __syncthreads();
  for (int idx = threadIdx.x; idx < 4608; idx += 256) {
    int ww = idx / 48, g2 = idx % 48;
    unsigned int lo = t[g2 * 2][ww];
    unsigned int hi = t[g2 * 2 + 1][ww];
    *(unsigned int*)(vHp + (size_t)(b * 96 + ww) * 24576 + c * 96 + g2 * 2) = lo | (hi << 16);
  }
}

// Merged attn: z=0 (b,h-row) e_w pass; z=1 (b,w-col) e_h pass (diag-masked).
__global__ __launch_bounds__(384, 3) void attn_fused(const u16* __restrict__ Qpt, const u16* __restrict__ Kpt,
                                                     const u16* __restrict__ vWp, const u16* __restrict__ vHp,
                                                     float* __restrict__ mW, float* __restrict__ sW,
                                                     float* __restrict__ mH, float* __restrict__ sH,
                                                     u16* __restrict__ tmpW, u16* __restrict__ tmpH) {
  __shared__ u16 probs[96 * 104];  // 19968 B
  __shared__ u16 vbuf[128 * 104];  // 26624 B
  const int p = blockIdx.x, b = blockIdx.y, z = blockIdx.z;
  const int tid = threadIdx.x;
  const int lane = tid & 63, wv = tid >> 6;
  const int cl = lane & 15, g = lane >> 4;
  const int kc = g * 8;
  const int w0 = wv * 16;
  const u16* Vp = z ? vHp : vWp;
  u16* tOut = z ? tmpH : tmpW;
  const size_t vbase = (size_t)(b * 96 + p) * 24576;
  const int ldr = tid / 12;        // 0..31
  const int ldc = (tid % 12) * 8;  // 0,8,...,88
  // prefetch half-0 V tile into regs (hides under QK^T + softmax)
  float4 vpre[4];
#pragma unroll
  for (int i = 0; i < 4; ++i)
    vpre[i] = *(const float4*)(Vp + vbase + (size_t)(ldr + 32 * i) * 96 + ldc);
  // row n of logit-index i: z=0 -> n = p*96+i ; z=1 -> n = i*96+p
  const size_t base = (size_t)b * ((size_t)NHW * 64) + (size_t)p * (z ? 64 : 6144);
  const size_t istride = z ? 6144 : 64;
  // QK^T: e[i = w0+4g+r][j = nt*16+cl]
  f32x4 eacc[6];
  {
    f16x8 aq = *(const f16x8*)(Qpt + base + (size_t)(w0 + cl) * istride + kc);
#pragma unroll
    for (int nt = 0; nt < 6; ++nt) {
      f16x8 bk = *(const f16x8*)(Kpt + base + (size_t)(nt * 16 + cl) * istride + 32 + kc);
      f32x4 zz = {0.f, 0.f, 0.f, 0.f};
      eacc[nt] = __builtin_amdgcn_mfma_f32_16x16x32_f16(aq, bk, zz, 0, 0, 0);
    }
  }
  // wave softmax per row r: max/sum across 6 nt + 16 col-lanes
#pragma unroll
  for (int r = 0; r < 4; ++r) {
    int i = w0 + 4 * g + r;
    float m = -1e30f;
#pragma unroll
    for (int nt = 0; nt < 6; ++nt) {
      float e = eacc[nt][r];
      if (z && (nt * 16 + cl) == i) { e = -1e30f; eacc[nt][r] = e; }
      m = fmaxf(m, e);
    }
    m = fmaxf(m, __shfl_xor(m, 1));
    m = fmaxf(m, __shfl_xor(m, 2));
    m = fmaxf(m, __shfl_xor(m, 4));
    m = fmaxf(m, __shfl_xor(m, 8));
    float s = 0.f;
#pragma unroll
    for (int nt = 0; nt < 6; ++nt) {
      float pv = __expf(eacc[nt][r] - m);
      eacc[nt][r] = pv;
      s += pv;
    }
    s += __shfl_xor(s, 1);
    s += __shfl_xor(s, 2);
    s += __shfl_xor(s, 4);
    s += __shfl_xor(s, 8);
#pragma unroll
    for (int nt = 0; nt < 6; ++nt)
      probs[i * 104 + nt * 16 + cl] = f2h(eacc[nt][r]);
    if (cl == 0) {
      size_t sidx = z ? ((size_t)(b * 96 + i) * 96 + p) : ((size_t)(b * 96 + p) * 96 + i);
      (z ? mH : mW)[sidx] = m;
      (z ? sH : sW)[sidx] = s;
    }
  }
  // stage half-0 into LDS; one barrier covers probs + vbuf
#pragma unroll
  for (int i = 0; i < 4; ++i)
    *(float4*)&vbuf[(ldr + 32 * i) * 104 + ldc] = vpre[i];
  __syncthreads();  // S1
  f16x8 af[3];
#pragma unroll
  for (int kt = 0; kt < 3; ++kt)
    af[kt] = *(const f16x8*)&probs[(w0 + cl) * 104 + kt * 32 + kc];
  // prefetch half-1 (consumed 4 barriers later)
#pragma unroll
  for (int i = 0; i < 4; ++i)
    vpre[i] = *(const float4*)(Vp + vbase + (size_t)(128 + ldr + 32 * i) * 96 + ldc);
  // half-0 MFMAs
  f32x4 acc[8];
#pragma unroll
  for (int nt = 0; nt < 8; ++nt) {
    f32x4 a = {0.f, 0.f, 0.f, 0.f};
#pragma unroll
    for (int kt = 0; kt < 3; ++kt) {
      f16x8 bf = *(const f16x8*)&vbuf[(nt * 16 + cl) * 104 + kt * 32 + kc];
      a = __builtin_amdgcn_mfma_f32_16x16x32_f16(af[kt], bf, a, 0, 0, 0);
    }
    acc[nt] = a;
  }
  __syncthreads();  // S2: all vbuf reads done
  // transpose acc into vbuf -> rows = channel, cols = i (contiguous)
#pragma unroll
  for (int nt = 0; nt < 8; ++nt) {
    int c2 = nt * 16 + cl;
    int wr = w0 + (g << 2);
#pragma unroll
    for (int r = 0; r < 4; ++r) vbuf[c2 * 104 + wr + r] = f2h(acc[nt][r]);
  }
  __syncthreads();  // S3
  // coalesced store half-0 (192B row runs)
  for (int idx = tid; idx < 1536; idx += 384) {
    int r = idx / 12, c4 = idx % 12;
    *(float4*)(tOut + vbase + (size_t)r * 96 + c4 * 8) = *(const float4*)&vbuf[r * 104 + c4 * 8];
  }
  __syncthreads();  // S4: vbuf free
  // stage half-1
#pragma unroll
  for (int i = 0; i < 4; ++i)
    *(float4*)&vbuf[(ldr + 32 * i) * 104 + ldc] = vpre[i];
  __syncthreads();  // S5
  // half-1 MFMAs
#pragma unroll
  for (int nt = 0; nt < 8; ++nt) {
    f32x4 a = {0.f, 0.f, 0.f, 0.f};
#pragma unroll
    for (int kt = 0; kt < 3; ++kt) {
      f16x8 bf = *(const f16x8*)&vbuf[(nt * 16 + cl) * 104 + kt * 32 + kc];
      a = __builtin_amdgcn_mfma_f32_16x16x32_f16(af[kt], bf, a, 0, 0, 0);
    }
    acc[nt] = a;
  }
  __syncthreads();  // S6
#pragma unroll
  for (int nt = 0; nt < 8; ++nt) {
    int c2 = nt * 16 + cl;
    int wr = w0 + (g << 2);
#pragma unroll
    for (int r = 0; r < 4; ++r) vbuf[c2 * 104 + wr + r] = f2h(acc[nt][r]);
  }
  __syncthreads();  // S7
  for (int idx = tid; idx < 1536; idx += 384) {
    int r = idx / 12, c4 = idx % 12;
    *(float4*)(tOut + vbase + (size_t)(128 + r) * 96 + c4 * 8) = *(const float4*)&vbuf[r * 104 + c4 * 8];
  }
}

// Exact concat-softmax rescale: m=max(mh,mw), s=sh*e^(mh-m)+sw*e^(mw-m); scl*=gamma/s.
__global__ __launch_bounds__(256) void scl_k(const float* __restrict__ mH, const float* __restrict__ sH,
                                             const float* __restrict__ mW, const float* __restrict__ sW,
                                             const float* __restrict__ gammaP, float* __restrict__ sclH,
                                             float* __restrict__ sclW) {
  int i = blockIdx.x * 256 + threadIdx.x;
  if (i >= Bn * 9216) return;
  float mh = mH[i], mw = mW[i];
  float m = fmaxf(mh, mw);
  float eh = __expf(mh - m), ew = __expf(mw - m);
  float s = sH[i] * eh + sW[i] * ew;
  float g = gammaP[0] / s;
  sclH[i] = g * eh;
  sclW[i] = g * ew;
}

// out[b][c][h][w] = x + tmpH[b][w][c][h]*sclH[h][w] + tmpW[b][h][c][w]*sclW[h][w]
__global__ __launch_bounds__(256) void tkomb(const u16* __restrict__ tmpH, const u16* __restrict__ tmpW,
                                             const float* __restrict__ x, const float* __restrict__ sclH,
                                             const float* __restrict__ sclW, float* __restrict__ out) {
  __shared__ u16 t[96][108];
  const int c = blockIdx.x, b = blockIdx.y;
  const int tid = threadIdx.x;
  for (int idx = tid; idx < 2304; idx += 256) {
    int w_ = idx / 24, h4 = idx % 24;
    *(ushort4*)&t[w_][h4 * 4] =
        *(const ushort4*)(tmpH + ((size_t)(b * 96 + w_) * 256 + c) * 96 + h4 * 4);
  }
  __syncthreads();
  for (int idx = tid; idx < 2304; idx += 256) {
    int h_ = idx / 24, w4 = idx % 24;
    size_t go = ((size_t)(b * 256 + c) * 96 + h_) * 96 + w4 * 4;
    float4 xv = *(const float4*)(x + go);
    ushort4 wvv = *(const ushort4*)(tmpW + ((size_t)(b * 96 + h_) * 256 + c) * 96 + w4 * 4);
    float4 sh4 = *(const float4*)(sclH + (size_t)(b * 96 + h_) * 96 + w4 * 4);
    float4 sw4 = *(const float4*)(sclW + (size_t)(b * 96 + h_) * 96 + w4 * 4);
    float4 ov;
    ov.x = xv.x + h2f(t[w4 * 4 + 0][h_]) * sh4.x + h2f(wvv.x) * sw4.x;
    ov.y = xv.y + h2f(t[w4 * 4 + 1][h_]) * sh4.y + h2f(wvv.y) * sw4.y;
    ov.z = xv.z + h2f(t[w4 * 4 + 2][h_]) * sh4.z + h2f(wvv.z) * sw4.z;
    ov.w = xv.w + h2f(t[w4 * 4 + 3][h_]) * sh4.w + h2f(wvv.w) * sw4.w;
    *(float4*)(out + go) = ov;
  }
}

extern "C" void kernel_launch(void* const* d_in, const int* in_sizes, int n_in,
                              void* d_out, int out_size, void* d_ws, size_t ws_size,
                              hipStream_t stream) {
  const float* x0 = (const float*)d_in[0];
  const float* x1 = (const float*)d_in[1];
  const float* wq0 = (const float*)d_in[2];
  const float* bq0 = (const float*)d_in[3];
  const float* wk0 = (const float*)d_in[4];
  const float* bk0 = (const float*)d_in[5];
  const float* wv0 = (const float*)d_in[6];
  const float* bv0 = (const float*)d_in[7];
  const float* wq1 = (const float*)d_in[8];
  const float* bq1 = (const float*)d_in[9];
  const float* wk1 = (const float*)d_in[10];
  const float* bk1 = (const float*)d_in[11];
  const float* wv1 = (const float*)d_in[12];
  const float* bv1 = (const float*)d_in[13];
  const float* gamma = (const float*)d_in[14];
  float* out = (float*)d_out;

  char* ws = (char*)d_ws;
  size_t off = 0;
  auto alloc = [&](size_t bytes) -> void* {
    void* ptr = ws + off;
    off += (bytes + 255) & ~(size_t)255;
    return ptr;
  };
  const size_t SZ_P = (size_t)Bn * NHW * 64 * 2;   // 9.4 MB (f16)
  const size_t SZ_V = (size_t)Bn * NHW * Cn * 2;   // 37.7 MB
  const size_t SZ_S = (size_t)Bn * 9216 * 4;       // 294 KB
  u16* Pt0 = (u16*)alloc(SZ_P);
  u16* Pt1 = (u16*)alloc(SZ_P);
  u16* vW0 = (u16*)alloc(SZ_V);
  u16* vW1 = (u16*)alloc(SZ_V);
  u16* vH0 = (u16*)alloc(SZ_V);
  u16* vH1 = (u16*)alloc(SZ_V);
  u16* tmpW = (u16*)alloc(SZ_V);
  u16* tmpH = (u16*)alloc(SZ_V);
  u16* Wall0 = (u16*)alloc(320 * 256 * 2);
  u16* Wall1 = (u16*)alloc(320 * 256 * 2);
  float* ball0 = (float*)alloc(320 * 4);
  float* ball1 = (float*)alloc(320 * 4);
  float* mH = (float*)alloc(SZ_S);
  float* sH = (float*)alloc(SZ_S);
  float* mW = (float*)alloc(SZ_S);
  float* sW = (float*)alloc(SZ_S);
  float* sclH = (float*)alloc(SZ_S);
  float* sclW = (float*)alloc(SZ_S);
  (void)ws_size; (void)in_sizes; (void)n_in; (void)out_size;

  pack_all<<<320, 256, 0, stream>>>(wq0, bq0, wk0, bk0, wv0, bv0, Wall0, ball0);
  pack_all<<<320, 256, 0, stream>>>(wq1, bq1, wk1, bk1, wv1, bv1, Wall1, ball1);

  dim3 gp(96, Bn), gc(256, Bn), gt(256, Bn, 2), ga(96, Bn, 2);
  proj_all<<<gp, 256, 0, stream>>>(x0, Wall0, ball0, Pt0, vW0);
  proj_all<<<gp, 256, 0, stream>>>(x1, Wall1, ball1, Pt1, vW1);
  vtrans<<<gt, 256, 0, stream>>>(vW0, vW1, vH0, vH1);

  // pair 0: cat0 = gamma * attend(q1, k0, v0) + x0
  attn_fused<<<ga, 384, 0, stream>>>(Pt1, Pt0, vW0, vH0, mW, sW, mH, sH, tmpW, tmpH);
  scl_k<<<288, 256, 0, stream>>>(mH, sH, mW, sW, gamma, sclH, sclW);
  tkomb<<<gc, 256, 0, stream>>>(tmpH, tmpW, x0, sclH, sclW, out);

  // pair 1: cat1 = gamma * attend(q0, k1, v1) + x1
  attn_fused<<<ga, 384, 0, stream>>>(Pt0, Pt1, vW1, vH1, mW, sW, mH, sH, tmpW, tmpH);
  scl_k<<<288, 256, 0, stream>>>(mH, sH, mW, sW, gamma, sclH, sclW);
  tkomb<<<gc, 256, 0, stream>>>(tmpH, tmpW, x1, sclH, sclW, out + (size_t)Bn * Cn * NHW);
}

// Round 10
// 321.027 us; speedup vs baseline: 1.2365x; 1.1649x over previous
//
#include <hip/hip_runtime.h>
#include <hip/hip_bf16.h>

// CrissCross attention, B=8 C=256 H=W=96 CQ=32. Flash-style split softmax, fp16.
// 6 dispatches total (pairs merged via blockIdx.z everywhere):
//  pack_all : [wq|wk|wv] -> f16 Wall[320][256] + fp32 ball[320], both inputs
//  proj_all : 512-thr 8-wave f16-MFMA blocks (acc[5][3]=60 VGPR -> 4 waves/SIMD):
//             x row-tile staged once -> Pt[b][n][64] f16 + vW[b][h][c][w] f16
//  vtrans   : vW* -> vH*[b][w][c][g]
//  attn     : z&1: 0 = (b,h) e_w pass, 1 = (b,w) e_h pass (diag mask); z>>1 = pair.
//             Round-6-proven structure: q/k cooperatively staged to LDS, MFMA QK^T,
//             in-register wave softmax, probs->LDS, V staged per 128-ch half,
//             PV MFMA, LDS-transposed coalesced stores.
//  scl      : exact concat-softmax rescale (gamma folded), both pairs
//  tkomb    : out = x + tmpH^T*sclH + tmpW*sclW (transpose fused), both pairs

#define Bn 8
#define Cn 256
#define NHW 9216
#define PT_BS ((size_t)NHW * 64)

typedef unsigned short u16;
typedef __attribute__((ext_vector_type(8))) _Float16 f16x8;
typedef __attribute__((ext_vector_type(4))) float f32x4;

__device__ __forceinline__ float h2f(u16 v) {
  _Float16 h;
  __builtin_memcpy(&h, &v, 2);
  return (float)h;
}
__device__ __forceinline__ u16 f2h(float f) {
  _Float16 h = (_Float16)f;
  u16 v;
  __builtin_memcpy(&v, &h, 2);
  return v;
}

__global__ __launch_bounds__(256) void pack_all(const float* __restrict__ wq0, const float* __restrict__ bq0,
                                                const float* __restrict__ wk0, const float* __restrict__ bk0,
                                                const float* __restrict__ wv0, const float* __restrict__ bv0,
                                                const float* __restrict__ wq1, const float* __restrict__ bq1,
                                                const float* __restrict__ wk1, const float* __restrict__ bk1,
                                                const float* __restrict__ wv1, const float* __restrict__ bv1,
                                                u16* __restrict__ Wall0, float* __restrict__ ball0,
                                                u16* __restrict__ Wall1, float* __restrict__ ball1) {
  const int pr = blockIdx.y;
  const float* wq = pr ? wq1 : wq0;
  const float* bq = pr ? bq1 : bq0;
  const float* wk = pr ? wk1 : wk0;
  const float* bk = pr ? bk1 : bk0;
  const float* wv = pr ? wv1 : wv0;
  const float* bv = pr ? bv1 : bv0;
  u16* Wall = pr ? Wall1 : Wall0;
  float* ball = pr ? ball1 : ball0;
  int i = blockIdx.x * 256 + threadIdx.x;
  if (i < 320 * 256) {
    int o = i >> 8, c = i & 255;
    float v = (o < 32) ? wq[o * 256 + c] : (o < 64) ? wk[(o - 32) * 256 + c] : wv[(o - 64) * 256 + c];
    Wall[i] = f2h(v);
  }
  if (i < 320) ball[i] = (i < 32) ? bq[i] : (i < 64) ? bk[i - 32] : bv[i - 64];
}

// Fused projection: block (h, b, pair). 512 threads = 8 waves (mg = wv>>1, ng = wv&1).
// Wave (mg,ng): m-tiles {mg+4j, j=0..4} (j=0 -> qk tile), n-tiles ng*48 + {0,16,32}.
__global__ __launch_bounds__(512, 4) void proj_all(const float* __restrict__ X0, const float* __restrict__ X1,
                                                   const u16* __restrict__ Wall0, const u16* __restrict__ Wall1,
                                                   const float* __restrict__ ball0, const float* __restrict__ ball1,
                                                   u16* __restrict__ Pt0, u16* __restrict__ Pt1,
                                                   u16* __restrict__ vW0, u16* __restrict__ vW1) {
  __shared__ u16 xs[96][264];  // f16 x-tile [n][cin], 50688 B
  u16* sO = &xs[0][0];         // overlay [128][104] for v epilogue
  const int h = blockIdx.x, b = blockIdx.y, pr = blockIdx.z;
  const float* X = pr ? X1 : X0;
  const u16* Wall = pr ? Wall1 : Wall0;
  const float* ball = pr ? ball1 : ball0;
  u16* Pt = pr ? Pt1 : Pt0;
  u16* vW = pr ? vW1 : vW0;
  const int tid = threadIdx.x;
  const float* Xb = X + (size_t)b * Cn * NHW + h * 96;
  for (int idx = tid; idx < 6144; idx += 512) {
    int cin = idx / 24, n4 = idx % 24;
    float4 v = *(const float4*)(Xb + (size_t)cin * NHW + n4 * 4);
    xs[n4 * 4 + 0][cin] = f2h(v.x);
    xs[n4 * 4 + 1][cin] = f2h(v.y);
    xs[n4 * 4 + 2][cin] = f2h(v.z);
    xs[n4 * 4 + 3][cin] = f2h(v.w);
  }
  __syncthreads();
  const int lane = tid & 63, wv = tid >> 6;  // wv 0..7
  const int mg = wv >> 1, ng = wv & 1;
  const int arow = lane & 15;
  const int g = lane >> 4;
  const int kc = g * 8;
  f32x4 acc[5][3] = {};
#pragma unroll
  for (int kk = 0; kk < 8; ++kk) {
    f16x8 a5[5], b3[3];
#pragma unroll
    for (int j = 0; j < 5; ++j)
      a5[j] = *(const f16x8*)(Wall + (size_t)((mg + 4 * j) * 16 + arow) * 256 + kk * 32 + kc);
#pragma unroll
    for (int nt = 0; nt < 3; ++nt)
      b3[nt] = *(const f16x8*)&xs[ng * 48 + nt * 16 + arow][kk * 32 + kc];
#pragma unroll
    for (int j = 0; j < 5; ++j)
#pragma unroll
      for (int nt = 0; nt < 3; ++nt)
        acc[j][nt] = __builtin_amdgcn_mfma_f32_16x16x32_f16(a5[j], b3[nt], acc[j][nt], 0, 0, 0);
  }
  // qk epilogue: all 8 waves; o = mg*16 + 4g + rr
  {
    u16* Ptb = Pt + (size_t)b * PT_BS;
    float4 bv = *(const float4*)(ball + mg * 16 + (g << 2));
#pragma unroll
    for (int nt = 0; nt < 3; ++nt) {
      int n = h * 96 + ng * 48 + nt * 16 + arow;
      f32x4 a = acc[0][nt];
      ushort4 r;
      r.x = f2h(a[0] + bv.x); r.y = f2h(a[1] + bv.y);
      r.z = f2h(a[2] + bv.z); r.w = f2h(a[3] + bv.w);
      *(ushort4*)&Ptb[(size_t)n * 64 + mg * 16 + (g << 2)] = r;
    }
  }
  __syncthreads();
  // v epilogue: 2 rounds of 128 channels; round r covers v-tiles [8r, 8r+8)
  for (int r = 0; r < 2; ++r) {
#pragma unroll
    for (int jj = 0; jj < 2; ++jj) {
      int j = 2 * r + 1 + jj;          // acc row
      int vt = mg + 8 * r + 4 * jj;    // global v-tile (16 ch)
      float4 bv = *(const float4*)(ball + 64 + vt * 16 + (g << 2));
      float ba[4] = {bv.x, bv.y, bv.z, bv.w};
      int lrow0 = (mg + 4 * jj) * 16 + (g << 2);
#pragma unroll
      for (int nt = 0; nt < 3; ++nt) {
        int col = ng * 48 + nt * 16 + arow;
#pragma unroll
        for (int rr = 0; rr < 4; ++rr)
          sO[(lrow0 + rr) * 104 + col] = f2h(acc[j][nt][rr] + ba[rr]);
      }
    }
    __syncthreads();
    for (int idx = tid; idx < 1536; idx += 512) {
      int cc = idx / 12, c4 = idx % 12;
      *(float4*)(vW + ((size_t)(b * 96 + h) * 256 + r * 128 + cc) * 96 + c4 * 8) =
          *(const float4*)&sO[cc * 104 + c4 * 8];
    }
    __syncthreads();
  }
}

// vH[b][w][c][g] = vW[b][g][c][w], both pairs (z selects)
__global__ __launch_bounds__(256) void vtrans(const u16* __restrict__ vW0, const u16* __restrict__ vW1,
                                              u16* __restrict__ vH0, u16* __restrict__ vH1) {
  __shared__ u16 t[96][98];
  const int c = blockIdx.x, b = blockIdx.y;
  const u16* vWp = blockIdx.z ? vW1 : vW0;
  u16* vHp = blockIdx.z ? vH1 : vH0;
  for (int idx = threadIdx.x; idx < 4608; idx += 256) {
    int hh = idx / 48, w2 = idx % 48;
    *(unsigned int*)&t[hh][w2 * 2] =
        *(const unsigned int*)(vWp + (size_t)(b * 96 + hh) * 24576 + c * 96 + w2 * 2);
  }
  __syncthreads();
  for (int idx = threadIdx.x; idx < 4608; idx += 256) {
    int ww = idx / 48, g2 = idx % 48;
    unsigned int lo = t[g2 * 2][ww];
    unsigned int hi = t[g2 * 2 + 1][ww];
    *(unsigned int*)(vHp + (size_t)(b * 96 + ww) * 24576 + c * 96 + g2 * 2) = lo | (hi << 16);
  }
}

// attn: pass = z&1 (0: (b,h) e_w; 1: (b,w) e_h diag-masked), pair = z>>1.
// Round-6 structure: LDS-staged q/k, MFMA QK^T, in-reg softmax, staged V halves,
// PV MFMA, LDS-transposed coalesced stores.
__global__ __launch_bounds__(384, 3) void attn_fused(const u16* __restrict__ Pt0, const u16* __restrict__ Pt1,
                                                     const u16* __restrict__ vW0, const u16* __restrict__ vH0,
                                                     const u16* __restrict__ vW1, const u16* __restrict__ vH1,
                                                     float* __restrict__ mWs, float* __restrict__ sWs,
                                                     float* __restrict__ mHs, float* __restrict__ sHs,
                                                     u16* __restrict__ tmpW0, u16* __restrict__ tmpH0,
                                                     u16* __restrict__ tmpW1, u16* __restrict__ tmpH1) {
  __shared__ __align__(16) char smem[46592];
  u16* vbuf = (u16*)smem;             // [128][104]
  u16* qs = (u16*)smem;               // [96][40] overlays vbuf
  u16* ks = (u16*)(smem + 7680);      // [96][40]
  u16* probs = (u16*)(smem + 26624);  // [96][104]
  const int p = blockIdx.x, b = blockIdx.y, z = blockIdx.z;
  const int pass = z & 1, pair = z >> 1;
  const u16* Qpt = pair ? Pt0 : Pt1;  // pair0: q1,k0,v0 ; pair1: q0,k1,v1
  const u16* Kpt = pair ? Pt1 : Pt0;
  const u16* Vp = pair ? (pass ? vH1 : vW1) : (pass ? vH0 : vW0);
  u16* tOut = pair ? (pass ? tmpH1 : tmpW1) : (pass ? tmpH0 : tmpW0);
  float* mOut = (pass ? mHs : mWs) + (size_t)pair * (Bn * 9216);
  float* sOut = (pass ? sHs : sWs) + (size_t)pair * (Bn * 9216);
  const int tid = threadIdx.x;
  const size_t nbase = (size_t)b * PT_BS;
  const size_t rowoff = pass ? (size_t)p * 64 : (size_t)p * 6144;
  const int rstride = pass ? 6144 : 64;
  // stage q (ch 0..31) and k (ch 32..63) rows as f16 (coalesced 128B-row bursts)
  for (int idx = tid; idx < 768; idx += 384) {
    int i = idx >> 3, c8 = idx & 7;
    const u16* src = (c8 < 4)
        ? Qpt + nbase + rowoff + (size_t)i * rstride + c8 * 8
        : Kpt + nbase + rowoff + (size_t)i * rstride + 32 + (c8 - 4) * 8;
    float4 v = *(const float4*)src;
    u16* dst = (c8 < 4) ? &qs[i * 40 + c8 * 8] : &ks[i * 40 + (c8 - 4) * 8];
    *(float4*)dst = v;
  }
  __syncthreads();
  const int lane = tid & 63, wv = tid >> 6;
  const int cl = lane & 15, g = lane >> 4;
  const int kc = g * 8;
  const int w0 = wv * 16;
  // QK^T: e[i = w0+4g+r][j = nt*16+cl]
  f32x4 eacc[6];
  {
    f16x8 aq = *(const f16x8*)&qs[(w0 + cl) * 40 + kc];
#pragma unroll
    for (int nt = 0; nt < 6; ++nt) {
      f16x8 bk = *(const f16x8*)&ks[(nt * 16 + cl) * 40 + kc];
      f32x4 zz = {0.f, 0.f, 0.f, 0.f};
      eacc[nt] = __builtin_amdgcn_mfma_f32_16x16x32_f16(aq, bk, zz, 0, 0, 0);
    }
  }
  // wave softmax per row r
#pragma unroll
  for (int r = 0; r < 4; ++r) {
    int i = w0 + 4 * g + r;
    float m = -1e30f;
#pragma unroll
    for (int nt = 0; nt < 6; ++nt) {
      float e = eacc[nt][r];
      if (pass && (nt * 16 + cl) == i) { e = -1e30f; eacc[nt][r] = e; }
      m = fmaxf(m, e);
    }
    m = fmaxf(m, __shfl_xor(m, 1));
    m = fmaxf(m, __shfl_xor(m, 2));
    m = fmaxf(m, __shfl_xor(m, 4));
    m = fmaxf(m, __shfl_xor(m, 8));
    float s = 0.f;
#pragma unroll
    for (int nt = 0; nt < 6; ++nt) {
      float pv = __expf(eacc[nt][r] - m);
      eacc[nt][r] = pv;
      s += pv;
    }
    s += __shfl_xor(s, 1);
    s += __shfl_xor(s, 2);
    s += __shfl_xor(s, 4);
    s += __shfl_xor(s, 8);
#pragma unroll
    for (int nt = 0; nt < 6; ++nt)
      probs[i * 104 + nt * 16 + cl] = f2h(eacc[nt][r]);
    if (cl == 0) {
      size_t sidx = pass ? ((size_t)(b * 96 + i) * 96 + p) : ((size_t)(b * 96 + p) * 96 + i);
      mOut[sidx] = m;
      sOut[sidx] = s;
    }
  }
  __syncthreads();
  f16x8 af[3];
#pragma unroll
  for (int kt = 0; kt < 3; ++kt)
    af[kt] = *(const f16x8*)&probs[(w0 + cl) * 104 + kt * 32 + kc];
  const size_t vbase = (size_t)(b * 96 + p) * 24576;
  for (int half = 0; half < 2; ++half) {
    for (int idx = tid; idx < 1536; idx += 384) {
      int r = idx / 12, c4 = idx % 12;
      *(float4*)&vbuf[r * 104 + c4 * 8] =
          *(const float4*)(Vp + vbase + (size_t)(half * 128 + r) * 96 + c4 * 8);
    }
    __syncthreads();
    f32x4 acc[8];
#pragma unroll
    for (int nt = 0; nt < 8; ++nt) {
      f32x4 a = {0.f, 0.f, 0.f, 0.f};
#pragma unroll
      for (int kt = 0; kt < 3; ++kt) {
        f16x8 bf = *(const f16x8*)&vbuf[(nt * 16 + cl) * 104 + kt * 32 + kc];
        a = __builtin_amdgcn_mfma_f32_16x16x32_f16(af[kt], bf, a, 0, 0, 0);
      }
      acc[nt] = a;
    }
    __syncthreads();
#pragma unroll
    for (int nt = 0; nt < 8; ++nt) {
      int c2 = nt * 16 + cl;
      int wr = w0 + (g << 2);
#pragma unroll
      for (int r = 0; r < 4; ++r) vbuf[c2 * 104 + wr + r] = f2h(acc[nt][r]);
    }
    __syncthreads();
    for (int idx = tid; idx < 1536; idx += 384) {
      int r = idx / 12, c4 = idx % 12;
      *(float4*)(tOut + vbase + (size_t)(half * 128 + r) * 96 + c4 * 8) =
          *(const float4*)&vbuf[r * 104 + c4 * 8];
    }
    __syncthreads();
  }
}

// Both pairs: i in [0, 2*Bn*9216)
__global__ __launch_bounds__(256) void scl_k(const float* __restrict__ mH, const float* __restrict__ sH,
                                             const float* __restrict__ mW, const float* __restrict__ sW,
                                             const float* __restrict__ gammaP, float* __restrict__ sclH,
                                             float* __restrict__ sclW) {
  int i = blockIdx.x * 256 + threadIdx.x;
  if (i >= 2 * Bn * 9216) return;
  float mh = mH[i], mw = mW[i];
  float m = fmaxf(mh, mw);
  float eh = __expf(mh - m), ew = __expf(mw - m);
  float s = sH[i] * eh + sW[i] * ew;
  float g = gammaP[0] / s;
  sclH[i] = g * eh;
  sclW[i] = g * ew;
}

// out[b][c][h][w] = x + tmpH[b][w][c][h]*sclH + tmpW[b][h][c][w]*sclW, pair = z
__global__ __launch_bounds__(256) void tkomb(const u16* __restrict__ tmpH0, const u16* __restrict__ tmpW0,
                                             const u16* __restrict__ tmpH1, const u16* __restrict__ tmpW1,
                                             const float* __restrict__ x0, const float* __restrict__ x1,
                                             const float* __restrict__ sclH, const float* __restrict__ sclW,
                                             float* __restrict__ out) {
  __shared__ u16 t[96][108];
  const int c = blockIdx.x, b = blockIdx.y, pr = blockIdx.z;
  const u16* tmpH = pr ? tmpH1 : tmpH0;
  const u16* tmpW = pr ? tmpW1 : tmpW0;
  const float* x = pr ? x1 : x0;
  const float* sH = sclH + (size_t)pr * (Bn * 9216);
  const float* sW = sclW + (size_t)pr * (Bn * 9216);
  float* o = out + (size_t)pr * Bn * Cn * NHW;
  const int tid = threadIdx.x;
  for (int idx = tid; idx < 2304; idx += 256) {
    int w_ = idx / 24, h4 = idx % 24;
    *(ushort4*)&t[w_][h4 * 4] =
        *(const ushort4*)(tmpH + ((size_t)(b * 96 + w_) * 256 + c) * 96 + h4 * 4);
  }
  __syncthreads();
  for (int idx = tid; idx < 2304; idx += 256) {
    int h_ = idx / 24, w4 = idx % 24;
    size_t go = ((size_t)(b * 256 + c) * 96 + h_) * 96 + w4 * 4;
    float4 xv = *(const float4*)(x + go);
    ushort4 wvv = *(const ushort4*)(tmpW + ((size_t)(b * 96 + h_) * 256 + c) * 96 + w4 * 4);
    float4 sh4 = *(const float4*)(sH + (size_t)(b * 96 + h_) * 96 + w4 * 4);
    float4 sw4 = *(const float4*)(sW + (size_t)(b * 96 + h_) * 96 + w4 * 4);
    float4 ov;
    ov.x = xv.x + h2f(t[w4 * 4 + 0][h_]) * sh4.x + h2f(wvv.x) * sw4.x;
    ov.y = xv.y + h2f(t[w4 * 4 + 1][h_]) * sh4.y + h2f(wvv.y) * sw4.y;
    ov.z = xv.z + h2f(t[w4 * 4 + 2][h_]) * sh4.z + h2f(wvv.z) * sw4.z;
    ov.w = xv.w + h2f(t[w4 * 4 + 3][h_]) * sh4.w + h2f(wvv.w) * sw4.w;
    *(float4*)(o + go) = ov;
  }
}

extern "C" void kernel_launch(void* const* d_in, const int* in_sizes, int n_in,
                              void* d_out, int out_size, void* d_ws, size_t ws_size,
                              hipStream_t stream) {
  const float* x0 = (const float*)d_in[0];
  const float* x1 = (const float*)d_in[1];
  const float* wq0 = (const float*)d_in[2];
  const float* bq0 = (const float*)d_in[3];
  const float* wk0 = (const float*)d_in[4];
  const float* bk0 = (const float*)d_in[5];
  const float* wv0 = (const float*)d_in[6];
  const float* bv0 = (const float*)d_in[7];
  const float* wq1 = (const float*)d_in[8];
  const float* bq1 = (const float*)d_in[9];
  const float* wk1 = (const float*)d_in[10];
  const float* bk1 = (const float*)d_in[11];
  const float* wv1 = (const float*)d_in[12];
  const float* bv1 = (const float*)d_in[13];
  const float* gamma = (const float*)d_in[14];
  float* out = (float*)d_out;

  char* ws = (char*)d_ws;
  size_t off = 0;
  auto alloc = [&](size_t bytes) -> void* {
    void* ptr = ws + off;
    off += (bytes + 255) & ~(size_t)255;
    return ptr;
  };
  const size_t SZ_P = (size_t)Bn * NHW * 64 * 2;   // 9.4 MB (f16)
  const size_t SZ_V = (size_t)Bn * NHW * Cn * 2;   // 37.7 MB
  const size_t SZ_S = (size_t)Bn * 9216 * 4;       // 294 KB
  u16* Pt0 = (u16*)alloc(SZ_P);
  u16* Pt1 = (u16*)alloc(SZ_P);
  u16* vW0 = (u16*)alloc(SZ_V);
  u16* vW1 = (u16*)alloc(SZ_V);
  u16* vH0 = (u16*)alloc(SZ_V);
  u16* vH1 = (u16*)alloc(SZ_V);
  u16* tmpW0 = (u16*)alloc(SZ_V);
  u16* tmpH0 = (u16*)alloc(SZ_V);
  u16* tmpW1 = (u16*)alloc(SZ_V);
  u16* tmpH1 = (u16*)alloc(SZ_V);
  u16* Wall0 = (u16*)alloc(320 * 256 * 2);
  u16* Wall1 = (u16*)alloc(320 * 256 * 2);
  float* ball0 = (float*)alloc(320 * 4);
  float* ball1 = (float*)alloc(320 * 4);
  float* mH = (float*)alloc(2 * SZ_S);
  float* sH = (float*)alloc(2 * SZ_S);
  float* mW = (float*)alloc(2 * SZ_S);
  float* sW = (float*)alloc(2 * SZ_S);
  float* sclH = (float*)alloc(2 * SZ_S);
  float* sclW = (float*)alloc(2 * SZ_S);
  (void)ws_size; (void)in_sizes; (void)n_in; (void)out_size;

  dim3 gpk(320, 2), gp(96, Bn, 2), gt(256, Bn, 2), ga(96, Bn, 4), gc(256, Bn, 2);
  pack_all<<<gpk, 256, 0, stream>>>(wq0, bq0, wk0, bk0, wv0, bv0,
                                    wq1, bq1, wk1, bk1, wv1, bv1,
                                    Wall0, ball0, Wall1, ball1);
  proj_all<<<gp, 512, 0, stream>>>(x0, x1, Wall0, Wall1, ball0, ball1, Pt0, Pt1, vW0, vW1);
  vtrans<<<gt, 256, 0, stream>>>(vW0, vW1, vH0, vH1);
  attn_fused<<<ga, 384, 0, stream>>>(Pt0, Pt1, vW0, vH0, vW1, vH1,
                                     mW, sW, mH, sH, tmpW0, tmpH0, tmpW1, tmpH1);
  scl_k<<<576, 256, 0, stream>>>(mH, sH, mW, sW, gamma, sclH, sclW);
  tkomb<<<gc, 256, 0, stream>>>(tmpH0, tmpW0, tmpH1, tmpW1, x0, x1, sclH, sclW, out);
}

// Round 11
// 317.600 us; speedup vs baseline: 1.2498x; 1.0108x over previous
//
#include <hip/hip_runtime.h>
#include <hip/hip_bf16.h>

// CrissCross attention, B=8 C=256 H=W=96 CQ=32. Flash-style split softmax, fp16.
// 6 dispatches total (pairs merged via blockIdx.z everywhere):
//  pack_all : [wq|wk|wv] -> f16 Wall[320][256] + fp32 ball[320], both inputs
//  proj_all : 512-thr 8-wave f16-MFMA blocks; x staged via 4x4 register-block
//             transpose + XOR-swizzled LDS (kills the 12-way bank conflict of
//             scalar transposed writes) -> Pt[b][n][64] f16 + vW[b][h][c][w] f16
//  vtrans   : vW* -> vH*[b][w][c][g]
//  attn     : z&1: 0 = (b,h) e_w pass, 1 = (b,w) e_h pass (diag mask); z>>1 = pair.
//             LDS-staged q/k, MFMA QK^T, in-reg wave softmax, staged V halves,
//             PV MFMA, LDS-transposed coalesced stores.
//  scl      : exact concat-softmax rescale (gamma folded), both pairs
//  tkomb    : out = x + tmpH^T*sclH + tmpW*sclW (transpose fused), both pairs

#define Bn 8
#define Cn 256
#define NHW 9216
#define PT_BS ((size_t)NHW * 64)

typedef unsigned short u16;
typedef __attribute__((ext_vector_type(8))) _Float16 f16x8;
typedef __attribute__((ext_vector_type(4))) float f32x4;

__device__ __forceinline__ float h2f(u16 v) {
  _Float16 h;
  __builtin_memcpy(&h, &v, 2);
  return (float)h;
}
__device__ __forceinline__ u16 f2h(float f) {
  _Float16 h = (_Float16)f;
  u16 v;
  __builtin_memcpy(&v, &h, 2);
  return v;
}

__global__ __launch_bounds__(256) void pack_all(const float* __restrict__ wq0, const float* __restrict__ bq0,
                                                const float* __restrict__ wk0, const float* __restrict__ bk0,
                                                const float* __restrict__ wv0, const float* __restrict__ bv0,
                                                const float* __restrict__ wq1, const float* __restrict__ bq1,
                                                const float* __restrict__ wk1, const float* __restrict__ bk1,
                                                const float* __restrict__ wv1, const float* __restrict__ bv1,
                                                u16* __restrict__ Wall0, float* __restrict__ ball0,
                                                u16* __restrict__ Wall1, float* __restrict__ ball1) {
  const int pr = blockIdx.y;
  const float* wq = pr ? wq1 : wq0;
  const float* bq = pr ? bq1 : bq0;
  const float* wk = pr ? wk1 : wk0;
  const float* bk = pr ? bk1 : bk0;
  const float* wv = pr ? wv1 : wv0;
  const float* bv = pr ? bv1 : bv0;
  u16* Wall = pr ? Wall1 : Wall0;
  float* ball = pr ? ball1 : ball0;
  int i = blockIdx.x * 256 + threadIdx.x;
  if (i < 320 * 256) {
    int o = i >> 8, c = i & 255;
    float v = (o < 32) ? wq[o * 256 + c] : (o < 64) ? wk[(o - 32) * 256 + c] : wv[(o - 64) * 256 + c];
    Wall[i] = f2h(v);
  }
  if (i < 320) ball[i] = (i < 32) ? bq[i] : (i < 64) ? bk[i - 32] : bv[i - 64];
}

// Fused projection: block (h, b, pair). 512 threads = 8 waves (mg = wv>>1, ng = wv&1).
// Wave (mg,ng): m-tiles {mg+4j, j=0..4} (j=0 -> qk tile), n-tiles ng*48 + {0,16,32}.
// xs element (row n, col k) lives at xs[row*264 + (col ^ (((row>>2)&7)<<3))]:
// swizzle bits 3-5 keep 4-u16 write runs and 8-u16 read runs contiguous+aligned.
__global__ __launch_bounds__(512, 4) void proj_all(const float* __restrict__ X0, const float* __restrict__ X1,
                                                   const u16* __restrict__ Wall0, const u16* __restrict__ Wall1,
                                                   const float* __restrict__ ball0, const float* __restrict__ ball1,
                                                   u16* __restrict__ Pt0, u16* __restrict__ Pt1,
                                                   u16* __restrict__ vW0, u16* __restrict__ vW1) {
  __shared__ __align__(16) u16 xs[96 * 264];  // 50688 B, swizzled [n][cin]
  u16* sO = xs;                               // overlay [128][104] for v epilogue
  const int h = blockIdx.x, b = blockIdx.y, pr = blockIdx.z;
  const float* X = pr ? X1 : X0;
  const u16* Wall = pr ? Wall1 : Wall0;
  const float* ball = pr ? ball1 : ball0;
  u16* Pt = pr ? Pt1 : Pt0;
  u16* vW = pr ? vW1 : vW0;
  const int tid = threadIdx.x;
  const float* Xb = X + (size_t)b * Cn * NHW + h * 96;
  // staging: 1536 tasks = 64 cq (4-cin quads) x 24 n4 (4-n quads); 3 iters.
  for (int idx = tid; idx < 1536; idx += 512) {
    int cq = idx / 24, n4 = idx % 24;
    const float* src = Xb + (size_t)(4 * cq) * NHW + n4 * 4;
    float4 v0 = *(const float4*)(src);
    float4 v1 = *(const float4*)(src + NHW);
    float4 v2 = *(const float4*)(src + 2 * NHW);
    float4 v3 = *(const float4*)(src + 3 * NHW);
    u16 c0[4] = {f2h(v0.x), f2h(v0.y), f2h(v0.z), f2h(v0.w)};
    u16 c1[4] = {f2h(v1.x), f2h(v1.y), f2h(v1.z), f2h(v1.w)};
    u16 c2[4] = {f2h(v2.x), f2h(v2.y), f2h(v2.z), f2h(v2.w)};
    u16 c3[4] = {f2h(v3.x), f2h(v3.y), f2h(v3.z), f2h(v3.w)};
    int colb = (4 * cq) ^ ((n4 & 7) << 3);  // row>>2 == n4 for all 4 rows
#pragma unroll
    for (int j = 0; j < 4; ++j) {
      ushort4 wv4;
      wv4.x = c0[j]; wv4.y = c1[j]; wv4.z = c2[j]; wv4.w = c3[j];
      *(ushort4*)&xs[(4 * n4 + j) * 264 + colb] = wv4;
    }
  }
  __syncthreads();
  const int lane = tid & 63, wv = tid >> 6;  // wv 0..7
  const int mg = wv >> 1, ng = wv & 1;
  const int arow = lane & 15;
  const int g = lane >> 4;
  const int kc = g * 8;
  // per-nt row constants for swizzled fragment reads
  int rbase[3], rsw[3];
#pragma unroll
  for (int nt = 0; nt < 3; ++nt) {
    int row = ng * 48 + nt * 16 + arow;
    rbase[nt] = row * 264;
    rsw[nt] = ((row >> 2) & 7) << 3;
  }
  f32x4 acc[5][3] = {};
#pragma unroll
  for (int kk = 0; kk < 8; ++kk) {
    f16x8 a5[5], b3[3];
#pragma unroll
    for (int j = 0; j < 5; ++j)
      a5[j] = *(const f16x8*)(Wall + (size_t)((mg + 4 * j) * 16 + arow) * 256 + kk * 32 + kc);
#pragma unroll
    for (int nt = 0; nt < 3; ++nt)
      b3[nt] = *(const f16x8*)&xs[rbase[nt] + ((kk * 32 + kc) ^ rsw[nt])];
#pragma unroll
    for (int j = 0; j < 5; ++j)
#pragma unroll
      for (int nt = 0; nt < 3; ++nt)
        acc[j][nt] = __builtin_amdgcn_mfma_f32_16x16x32_f16(a5[j], b3[nt], acc[j][nt], 0, 0, 0);
  }
  // qk epilogue: all 8 waves; o = mg*16 + 4g + rr
  {
    u16* Ptb = Pt + (size_t)b * PT_BS;
    float4 bv = *(const float4*)(ball + mg * 16 + (g << 2));
#pragma unroll
    for (int nt = 0; nt < 3; ++nt) {
      int n = h * 96 + ng * 48 + nt * 16 + arow;
      f32x4 a = acc[0][nt];
      ushort4 r;
      r.x = f2h(a[0] + bv.x); r.y = f2h(a[1] + bv.y);
      r.z = f2h(a[2] + bv.z); r.w = f2h(a[3] + bv.w);
      *(ushort4*)&Ptb[(size_t)n * 64 + mg * 16 + (g << 2)] = r;
    }
  }
  __syncthreads();
  // v epilogue: 2 rounds of 128 channels; round r covers v-tiles [8r, 8r+8)
  for (int r = 0; r < 2; ++r) {
#pragma unroll
    for (int jj = 0; jj < 2; ++jj) {
      int j = 2 * r + 1 + jj;          // acc row
      int vt = mg + 8 * r + 4 * jj;    // global v-tile (16 ch)
      float4 bv = *(const float4*)(ball + 64 + vt * 16 + (g << 2));
      float ba[4] = {bv.x, bv.y, bv.z, bv.w};
      int lrow0 = (mg + 4 * jj) * 16 + (g << 2);
#pragma unroll
      for (int nt = 0; nt < 3; ++nt) {
        int col = ng * 48 + nt * 16 + arow;
#pragma unroll
        for (int rr = 0; rr < 4; ++rr)
          sO[(lrow0 + rr) * 104 + col] = f2h(acc[j][nt][rr] + ba[rr]);
      }
    }
    __syncthreads();
    for (int idx = tid; idx < 1536; idx += 512) {
      int cc = idx / 12, c4 = idx % 12;
      *(float4*)(vW + ((size_t)(b * 96 + h) * 256 + r * 128 + cc) * 96 + c4 * 8) =
          *(const float4*)&sO[cc * 104 + c4 * 8];
    }
    __syncthreads();
  }
}

// vH[b][w][c][g] = vW[b][g][c][w], both pairs (z selects)
__global__ __launch_bounds__(256) void vtrans(const u16* __restrict__ vW0, const u16* __restrict__ vW1,
                                              u16* __restrict__ vH0, u16* __restrict__ vH1) {
  __shared__ u16 t[96][98];
  const int c = blockIdx.x, b = blockIdx.y;
  const u16* vWp = blockIdx.z ? vW1 : vW0;
  u16* vHp = blockIdx.z ? vH1 : vH0;
  for (int idx = threadIdx.x; idx < 4608; idx += 256) {
    int hh = idx / 48, w2 = idx % 48;
    *(unsigned int*)&t[hh][w2 * 2] =
        *(const unsigned int*)(vWp + (size_t)(b * 96 + hh) * 24576 + c * 96 + w2 * 2);
  }
  __syncthreads();
  for (int idx = threadIdx.x; idx < 4608; idx += 256) {
    int ww = idx / 48, g2 = idx % 48;
    unsigned int lo = t[g2 * 2][ww];
    unsigned int hi = t[g2 * 2 + 1][ww];
    *(unsigned int*)(vHp + (size_t)(b * 96 + ww) * 24576 + c * 96 + g2 * 2) = lo | (hi << 16);
  }
}

// attn: pass = z&1 (0: (b,h) e_w; 1: (b,w) e_h diag-masked), pair = z>>1.
__global__ __launch_bounds__(384, 3) void attn_fused(const u16* __restrict__ Pt0, const u16* __restrict__ Pt1,
                                                     const u16* __restrict__ vW0, const u16* __restrict__ vH0,
                                                     const u16* __restrict__ vW1, const u16* __restrict__ vH1,
                                                     float* __restrict__ mWs, float* __restrict__ sWs,
                                                     float* __restrict__ mHs, float* __restrict__ sHs,
                                                     u16* __restrict__ tmpW0, u16* __restrict__ tmpH0,
                                                     u16* __restrict__ tmpW1, u16* __restrict__ tmpH1) {
  __shared__ __align__(16) char smem[46592];
  u16* vbuf = (u16*)smem;             // [128][104]
  u16* qs = (u16*)smem;               // [96][40] overlays vbuf
  u16* ks = (u16*)(smem + 7680);      // [96][40]
  u16* probs = (u16*)(smem + 26624);  // [96][104]
  const int p = blockIdx.x, b = blockIdx.y, z = blockIdx.z;
  const int pass = z & 1, pair = z >> 1;
  const u16* Qpt = pair ? Pt0 : Pt1;  // pair0: q1,k0,v0 ; pair1: q0,k1,v1
  const u16* Kpt = pair ? Pt1 : Pt0;
  const u16* Vp = pair ? (pass ? vH1 : vW1) : (pass ? vH0 : vW0);
  u16* tOut = pair ? (pass ? tmpH1 : tmpW1) : (pass ? tmpH0 : tmpW0);
  float* mOut = (pass ? mHs : mWs) + (size_t)pair * (Bn * 9216);
  float* sOut = (pass ? sHs : sWs) + (size_t)pair * (Bn * 9216);
  const int tid = threadIdx.x;
  const size_t nbase = (size_t)b * PT_BS;
  const size_t rowoff = pass ? (size_t)p * 64 : (size_t)p * 6144;
  const int rstride = pass ? 6144 : 64;
  for (int idx = tid; idx < 768; idx += 384) {
    int i = idx >> 3, c8 = idx & 7;
    const u16* src = (c8 < 4)
        ? Qpt + nbase + rowoff + (size_t)i * rstride + c8 * 8
        : Kpt + nbase + rowoff + (size_t)i * rstride + 32 + (c8 - 4) * 8;
    float4 v = *(const float4*)src;
    u16* dst = (c8 < 4) ? &qs[i * 40 + c8 * 8] : &ks[i * 40 + (c8 - 4) * 8];
    *(float4*)dst = v;
  }
  __syncthreads();
  const int lane = tid & 63, wv = tid >> 6;
  const int cl = lane & 15, g = lane >> 4;
  const int kc = g * 8;
  const int w0 = wv * 16;
  f32x4 eacc[6];
  {
    f16x8 aq = *(const f16x8*)&qs[(w0 + cl) * 40 + kc];
#pragma unroll
    for (int nt = 0; nt < 6; ++nt) {
      f16x8 bk = *(const f16x8*)&ks[(nt * 16 + cl) * 40 + kc];
      f32x4 zz = {0.f, 0.f, 0.f, 0.f};
      eacc[nt] = __builtin_amdgcn_mfma_f32_16x16x32_f16(aq, bk, zz, 0, 0, 0);
    }
  }
#pragma unroll
  for (int r = 0; r < 4; ++r) {
    int i = w0 + 4 * g + r;
    float m = -1e30f;
#pragma unroll
    for (int nt = 0; nt < 6; ++nt) {
      float e = eacc[nt][r];
      if (pass && (nt * 16 + cl) == i) { e = -1e30f; eacc[nt][r] = e; }
      m = fmaxf(m, e);
    }
    m = fmaxf(m, __shfl_xor(m, 1));
    m = fmaxf(m, __shfl_xor(m, 2));
    m = fmaxf(m, __shfl_xor(m, 4));
    m = fmaxf(m, __shfl_xor(m, 8));
    float s = 0.f;
#pragma unroll
    for (int nt = 0; nt < 6; ++nt) {
      float pv = __expf(eacc[nt][r] - m);
      eacc[nt][r] = pv;
      s += pv;
    }
    s += __shfl_xor(s, 1);
    s += __shfl_xor(s, 2);
    s += __shfl_xor(s, 4);
    s += __shfl_xor(s, 8);
#pragma unroll
    for (int nt = 0; nt < 6; ++nt)
      probs[i * 104 + nt * 16 + cl] = f2h(eacc[nt][r]);
    if (cl == 0) {
      size_t sidx = pass ? ((size_t)(b * 96 + i) * 96 + p) : ((size_t)(b * 96 + p) * 96 + i);
      mOut[sidx] = m;
      sOut[sidx] = s;
    }
  }
  __syncthreads();
  f16x8 af[3];
#pragma unroll
  for (int kt = 0; kt < 3; ++kt)
    af[kt] = *(const f16x8*)&probs[(w0 + cl) * 104 + kt * 32 + kc];
  const size_t vbase = (size_t)(b * 96 + p) * 24576;
  for (int half = 0; half < 2; ++half) {
    for (int idx = tid; idx < 1536; idx += 384) {
      int r = idx / 12, c4 = idx % 12;
      *(float4*)&vbuf[r * 104 + c4 * 8] =
          *(const float4*)(Vp + vbase + (size_t)(half * 128 + r) * 96 + c4 * 8);
    }
    __syncthreads();
    f32x4 acc[8];
#pragma unroll
    for (int nt = 0; nt < 8; ++nt) {
      f32x4 a = {0.f, 0.f, 0.f, 0.f};
#pragma unroll
      for (int kt = 0; kt < 3; ++kt) {
        f16x8 bf = *(const f16x8*)&vbuf[(nt * 16 + cl) * 104 + kt * 32 + kc];
        a = __builtin_amdgcn_mfma_f32_16x16x32_f16(af[kt], bf, a, 0, 0, 0);
      }
      acc[nt] = a;
    }
    __syncthreads();
#pragma unroll
    for (int nt = 0; nt < 8; ++nt) {
      int c2 = nt * 16 + cl;
      int wr = w0 + (g << 2);
#pragma unroll
      for (int r = 0; r < 4; ++r) vbuf[c2 * 104 + wr + r] = f2h(acc[nt][r]);
    }
    __syncthreads();
    for (int idx = tid; idx < 1536; idx += 384) {
      int r = idx / 12, c4 = idx % 12;
      *(float4*)(tOut + vbase + (size_t)(half * 128 + r) * 96 + c4 * 8) =
          *(const float4*)&vbuf[r * 104 + c4 * 8];
    }
    __syncthreads();
  }
}

// Both pairs: i in [0, 2*Bn*9216)
__global__ __launch_bounds__(256) void scl_k(const float* __restrict__ mH, const float* __restrict__ sH,
                                             const float* __restrict__ mW, const float* __restrict__ sW,
                                             const float* __restrict__ gammaP, float* __restrict__ sclH,
                                             float* __restrict__ sclW) {
  int i = blockIdx.x * 256 + threadIdx.x;
  if (i >= 2 * Bn * 9216) return;
  float mh = mH[i], mw = mW[i];
  float m = fmaxf(mh, mw);
  float eh = __expf(mh - m), ew = __expf(mw - m);
  float s = sH[i] * eh + sW[i] * ew;
  float g = gammaP[0] / s;
  sclH[i] = g * eh;
  sclW[i] = g * ew;
}

// out[b][c][h][w] = x + tmpH[b][w][c][h]*sclH + tmpW[b][h][c][w]*sclW, pair = z
__global__ __launch_bounds__(256) void tkomb(const u16* __restrict__ tmpH0, const u16* __restrict__ tmpW0,
                                             const u16* __restrict__ tmpH1, const u16* __restrict__ tmpW1,
                                             const float* __restrict__ x0, const float* __restrict__ x1,
                                             const float* __restrict__ sclH, const float* __restrict__ sclW,
                                             float* __restrict__ out) {
  __shared__ u16 t[96][108];
  const int c = blockIdx.x, b = blockIdx.y, pr = blockIdx.z;
  const u16* tmpH = pr ? tmpH1 : tmpH0;
  const u16* tmpW = pr ? tmpW1 : tmpW0;
  const float* x = pr ? x1 : x0;
  const float* sH = sclH + (size_t)pr * (Bn * 9216);
  const float* sW = sclW + (size_t)pr * (Bn * 9216);
  float* o = out + (size_t)pr * Bn * Cn * NHW;
  const int tid = threadIdx.x;
  for (int idx = tid; idx < 2304; idx += 256) {
    int w_ = idx / 24, h4 = idx % 24;
    *(ushort4*)&t[w_][h4 * 4] =
        *(const ushort4*)(tmpH + ((size_t)(b * 96 + w_) * 256 + c) * 96 + h4 * 4);
  }
  __syncthreads();
  for (int idx = tid; idx < 2304; idx += 256) {
    int h_ = idx / 24, w4 = idx % 24;
    size_t go = ((size_t)(b * 256 + c) * 96 + h_) * 96 + w4 * 4;
    float4 xv = *(const float4*)(x + go);
    ushort4 wvv = *(const ushort4*)(tmpW + ((size_t)(b * 96 + h_) * 256 + c) * 96 + w4 * 4);
    float4 sh4 = *(const float4*)(sH + (size_t)(b * 96 + h_) * 96 + w4 * 4);
    float4 sw4 = *(const float4*)(sW + (size_t)(b * 96 + h_) * 96 + w4 * 4);
    float4 ov;
    ov.x = xv.x + h2f(t[w4 * 4 + 0][h_]) * sh4.x + h2f(wvv.x) * sw4.x;
    ov.y = xv.y + h2f(t[w4 * 4 + 1][h_]) * sh4.y + h2f(wvv.y) * sw4.y;
    ov.z = xv.z + h2f(t[w4 * 4 + 2][h_]) * sh4.z + h2f(wvv.z) * sw4.z;
    ov.w = xv.w + h2f(t[w4 * 4 + 3][h_]) * sh4.w + h2f(wvv.w) * sw4.w;
    *(float4*)(o + go) = ov;
  }
}

extern "C" void kernel_launch(void* const* d_in, const int* in_sizes, int n_in,
                              void* d_out, int out_size, void* d_ws, size_t ws_size,
                              hipStream_t stream) {
  const float* x0 = (const float*)d_in[0];
  const float* x1 = (const float*)d_in[1];
  const float* wq0 = (const float*)d_in[2];
  const float* bq0 = (const float*)d_in[3];
  const float* wk0 = (const float*)d_in[4];
  const float* bk0 = (const float*)d_in[5];
  const float* wv0 = (const float*)d_in[6];
  const float* bv0 = (const float*)d_in[7];
  const float* wq1 = (const float*)d_in[8];
  const float* bq1 = (const float*)d_in[9];
  const float* wk1 = (const float*)d_in[10];
  const float* bk1 = (const float*)d_in[11];
  const float* wv1 = (const float*)d_in[12];
  const float* bv1 = (const float*)d_in[13];
  const float* gamma = (const float*)d_in[14];
  float* out = (float*)d_out;

  char* ws = (char*)d_ws;
  size_t off = 0;
  auto alloc = [&](size_t bytes) -> void* {
    void* ptr = ws + off;
    off += (bytes + 255) & ~(size_t)255;
    return ptr;
  };
  const size_t SZ_P = (size_t)Bn * NHW * 64 * 2;   // 9.4 MB (f16)
  const size_t SZ_V = (size_t)Bn * NHW * Cn * 2;   // 37.7 MB
  const size_t SZ_S = (size_t)Bn * 9216 * 4;       // 294 KB
  u16* Pt0 = (u16*)alloc(SZ_P);
  u16* Pt1 = (u16*)alloc(SZ_P);
  u16* vW0 = (u16*)alloc(SZ_V);
  u16* vW1 = (u16*)alloc(SZ_V);
  u16* vH0 = (u16*)alloc(SZ_V);
  u16* vH1 = (u16*)alloc(SZ_V);
  u16* tmpW0 = (u16*)alloc(SZ_V);
  u16* tmpH0 = (u16*)alloc(SZ_V);
  u16* tmpW1 = (u16*)alloc(SZ_V);
  u16* tmpH1 = (u16*)alloc(SZ_V);
  u16* Wall0 = (u16*)alloc(320 * 256 * 2);
  u16* Wall1 = (u16*)alloc(320 * 256 * 2);
  float* ball0 = (float*)alloc(320 * 4);
  float* ball1 = (float*)alloc(320 * 4);
  float* mH = (float*)alloc(2 * SZ_S);
  float* sH = (float*)alloc(2 * SZ_S);
  float* mW = (float*)alloc(2 * SZ_S);
  float* sW = (float*)alloc(2 * SZ_S);
  float* sclH = (float*)alloc(2 * SZ_S);
  float* sclW = (float*)alloc(2 * SZ_S);
  (void)ws_size; (void)in_sizes; (void)n_in; (void)out_size;

  dim3 gpk(320, 2), gp(96, Bn, 2), gt(256, Bn, 2), ga(96, Bn, 4), gc(256, Bn, 2);
  pack_all<<<gpk, 256, 0, stream>>>(wq0, bq0, wk0, bk0, wv0, bv0,
                                    wq1, bq1, wk1, bk1, wv1, bv1,
                                    Wall0, ball0, Wall1, ball1);
  proj_all<<<gp, 512, 0, stream>>>(x0, x1, Wall0, Wall1, ball0, ball1, Pt0, Pt1, vW0, vW1);
  vtrans<<<gt, 256, 0, stream>>>(vW0, vW1, vH0, vH1);
  attn_fused<<<ga, 384, 0, stream>>>(Pt0, Pt1, vW0, vH0, vW1, vH1,
                                     mW, sW, mH, sH, tmpW0, tmpH0, tmpW1, tmpH1);
  scl_k<<<576, 256, 0, stream>>>(mH, sH, mW, sW, gamma, sclH, sclW);
  tkomb<<<gc, 256, 0, stream>>>(tmpH0, tmpW0, tmpH1, tmpW1, x0, x1, sclH, sclW, out);
}